// Round 13
// baseline (206.596 us; speedup 1.0000x reference)
//
#include <hip/hip_runtime.h>
#include <cstdint>
#include <cstddef>

#define NB 2
#define SEQ 2048
#define DMODEL 2048
#define NHEAD 16
#define HDIM 128
#define NGRP 4
#define NKV (NGRP * HDIM)          // 512
#define NQKV (DMODEL + 2 * NKV)    // 3072
#define MROWS (NB * SEQ)           // 4096
// 1/sqrt(128) * log2(e): Q pre-scale so softmax uses exp2 directly
#define QSCALE_LOG2E 0.12751743f

typedef unsigned short u16_t;
typedef unsigned int u32_t;
typedef __bf16 bf16x8 __attribute__((ext_vector_type(8)));
typedef __bf16 bf16x4 __attribute__((ext_vector_type(4)));
typedef float f32x4 __attribute__((ext_vector_type(4)));

static __device__ __forceinline__ u16_t f2bf(float f) {
  u32_t u = __builtin_bit_cast(u32_t, f);
  u32_t r = u + 0x7FFFu + ((u >> 16) & 1u);
  return (u16_t)(r >> 16);
}

// ---------------- prep kernels ----------------

__global__ void k_cast_x(const float* __restrict__ x, u16_t* __restrict__ xb) {
  int i = blockIdx.x * 256 + threadIdx.x;          // group of 4 floats
  float4 v = ((const float4*)x)[i];
  uint2 pk;
  pk.x = (u32_t)f2bf(v.x) | ((u32_t)f2bf(v.y) << 16);
  pk.y = (u32_t)f2bf(v.z) | ((u32_t)f2bf(v.w) << 16);
  ((uint2*)xb)[i] = pk;
}

__global__ void k_tables(const float* __restrict__ rf, float* __restrict__ cosT,
                         float* __restrict__ sinT) {
  int i = blockIdx.x * 256 + threadIdx.x;          // < SEQ*HDIM/2
  float f = rf[i];
  cosT[i] = cosf(f);
  sinT[i] = sinf(f);
}

__global__ void k_bias(const float* __restrict__ bq, const float* __restrict__ bk,
                       const float* __restrict__ bv, float* __restrict__ bqkv) {
  int i = blockIdx.x * 256 + threadIdx.x;          // < NQKV
  float v = (i < DMODEL) ? bq[i] : (i < DMODEL + NKV ? bk[i - DMODEL] : bv[i - DMODEL - NKV]);
  bqkv[i] = v;
}

// W: [K][N] fp32 row-major -> Wt: [N][K] bf16 row-major
__global__ void k_transpose_cast(const float* __restrict__ W, int N,
                                 u16_t* __restrict__ Wt, int K) {
  __shared__ float tile[64][65];
  int n0 = blockIdx.x * 64, k0 = blockIdx.y * 64;
  int t = threadIdx.x;
#pragma unroll
  for (int pass = 0; pass < 4; ++pass) {
    int slot = pass * 256 + t;
    int r = slot >> 4, c4 = (slot & 15) * 4;
    float4 v = *(const float4*)(W + (size_t)(k0 + r) * N + n0 + c4);
    tile[r][c4] = v.x; tile[r][c4 + 1] = v.y; tile[r][c4 + 2] = v.z; tile[r][c4 + 3] = v.w;
  }
  __syncthreads();
  int nr = t >> 2, seg = t & 3;
  alignas(16) u16_t o[16];
#pragma unroll
  for (int kk = 0; kk < 16; ++kk) o[kk] = f2bf(tile[seg * 16 + kk][nr]);
  u16_t* dst = Wt + (size_t)(n0 + nr) * K + k0 + seg * 16;
  ((int4*)dst)[0] = ((const int4*)o)[0];
  ((int4*)dst)[1] = ((const int4*)o)[1];
}

// ---------------- GEMM: C[M][N] = A[M][K](bf16) * Bt[N][K](bf16)^T + bias ----------
// 128x128 tile, BK=32, 256 threads (4 waves, 2x2), per-wave 64x64 (acc[4][4]).
// Round-13: counted ledger (R11) + register pipeline (R12) via 3-slot LDS rotation:
//   region t: stage(t+2)->slot (t+2)%3         [issued FIRST]
//             vmcnt(4)  [retires stage(t+1), issued one FULL region ago;
//                        leaves stage(t+2) in flight -- never drained]
//             s_barrier #1 -> slot (t+1)%3 valid block-wide
//             MFMA(t, regs from last region)  || rdfrags(t+1 -> other reg set)
//             s_barrier #2
// Slot audit: stage(t+2) overwrites tile t-1's slot, last read region t-2,
// confirmed >=2 barriers earlier. Reg sets ping-pong by unroll-by-2.
// Plain 2D grid (L3-friendly, R9 lesson); source-preswizzled chunks.
// EPI 0: fp32 out.  EPI 1: QKV epilogue (RoPE, Q pre-scaled, V transposed).

template <int EPI>
__global__ __launch_bounds__(256, 2) void k_gemm(
    const u16_t* __restrict__ A, const u16_t* __restrict__ Bt, const float* __restrict__ bias,
    float* __restrict__ Cout, u16_t* __restrict__ Qb, u16_t* __restrict__ Kb,
    u16_t* __restrict__ Vt, const float* __restrict__ cosT, const float* __restrict__ sinT,
    int M, int N, int K) {
  // u16: A slots at s*4096 (s=0,1,2); B slots at 12288 + s*4096. 48KB total.
  __shared__ u16_t lds[24576];
  int tid = threadIdx.x;
  int wid = tid >> 6, lane = tid & 63;
  int l15 = lane & 15, l4 = lane >> 4;
  int wrow = wid >> 1, wcol = wid & 1;

  int m0 = blockIdx.y << 7, n0 = blockIdx.x << 7;

  f32x4 acc[4][4] = {};

  auto stage = [&](int t) {
    int slot3 = t % 3;
    u16_t* Al = lds + slot3 * 4096;
    u16_t* Bl = lds + 12288 + slot3 * 4096;
    int kbase = t * 32;
#pragma unroll
    for (int ss = 0; ss < 2; ++ss) {
      int slot = tid + ss * 256;
      int row = slot >> 2, c = slot & 3;
      int cs = c ^ (row & 3);
      __builtin_amdgcn_global_load_lds(
          (const __attribute__((address_space(1))) u32_t*)(A + (size_t)(m0 + row) * K + kbase + cs * 8),
          (__attribute__((address_space(3))) u32_t*)(Al + slot * 8), 16, 0, 0);
      __builtin_amdgcn_global_load_lds(
          (const __attribute__((address_space(1))) u32_t*)(Bt + (size_t)(n0 + row) * K + kbase + cs * 8),
          (__attribute__((address_space(3))) u32_t*)(Bl + slot * 8), 16, 0, 0);
    }
  };

  auto rdfrags = [&](int t, bf16x8 (&af)[4], bf16x8 (&bfr)[4]) {
    int slot3 = t % 3;
    const u16_t* Ac = lds + slot3 * 4096;
    const u16_t* Bc = lds + 12288 + slot3 * 4096;
    int chunk = l4 ^ (l15 & 3);
#pragma unroll
    for (int i = 0; i < 4; ++i)
      af[i] = *(const bf16x8*)(Ac + (wrow * 64 + i * 16 + l15) * 32 + chunk * 8);
#pragma unroll
    for (int j = 0; j < 4; ++j)
      bfr[j] = *(const bf16x8*)(Bc + (wcol * 64 + j * 16 + l15) * 32 + chunk * 8);
  };

  bf16x8 afA[4], bfA[4], afB[4], bfB[4];

  auto mfma16 = [&](bf16x8 (&af)[4], bf16x8 (&bfr)[4]) {
    __builtin_amdgcn_s_setprio(1);
#pragma unroll
    for (int i = 0; i < 4; ++i)
#pragma unroll
      for (int j = 0; j < 4; ++j)
        acc[i][j] = __builtin_amdgcn_mfma_f32_16x16x32_bf16(af[i], bfr[j], acc[i][j], 0, 0, 0);
    __builtin_amdgcn_s_setprio(0);
  };

  const int NT = K >> 5;   // 64 (even)

  // region t: see header comment
  auto region = [&](int t, bf16x8 (&aC)[4], bf16x8 (&bC)[4],
                    bf16x8 (&aN)[4], bf16x8 (&bN)[4]) {
    if (t + 2 < NT) {
      stage(t + 2);
      asm volatile("s_waitcnt vmcnt(4)" ::: "memory");   // tile t+1 landed; t+2 in flight
    } else {
      asm volatile("s_waitcnt vmcnt(0)" ::: "memory");   // tail drain
    }
    __builtin_amdgcn_s_barrier();                        // #1: slot (t+1)%3 valid
    __builtin_amdgcn_sched_barrier(0);
    if (t + 1 < NT) rdfrags(t + 1, aN, bN);              // LDS pipe (next tile)
    mfma16(aC, bC);                                      // matrix pipe (this tile)
    __builtin_amdgcn_sched_barrier(0);
    __builtin_amdgcn_s_barrier();                        // #2
    __builtin_amdgcn_sched_barrier(0);
  };

  // prologue: tiles 0,1 staged; slot0 published; frags(0) in regs
  stage(0);
  stage(1);
  asm volatile("s_waitcnt vmcnt(4)" ::: "memory");       // stage(0) landed
  __builtin_amdgcn_s_barrier();
  __builtin_amdgcn_sched_barrier(0);
  rdfrags(0, afA, bfA);

  for (int pp = 0; pp < NT / 2; ++pp) {
    region(2 * pp, afA, bfA, afB, bfB);
    region(2 * pp + 1, afB, bfB, afA, bfA);
  }

  if (EPI == 0) {
#pragma unroll
    for (int j = 0; j < 4; ++j) {
      int n = n0 + wcol * 64 + j * 16 + l15;
      float bs = bias[n];
#pragma unroll
      for (int i = 0; i < 4; ++i) {
        int mbase = m0 + wrow * 64 + i * 16 + l4 * 4;
#pragma unroll
        for (int r = 0; r < 4; ++r)
          Cout[(size_t)(mbase + r) * N + n] = acc[i][j][r] + bs;
      }
    }
  } else {
    bool isV = (n0 >= DMODEL + NKV);
    bool isK = (n0 >= DMODEL) && !isV;
#pragma unroll
    for (int j = 0; j < 4; ++j) {
      int n = n0 + wcol * 64 + j * 16 + l15;
      float bs = bias[n];
      int d = n & (HDIM - 1);
      int p = d >> 1;
      bool evn = !(d & 1);
#pragma unroll
      for (int i = 0; i < 4; ++i) {
        int mbase = m0 + wrow * 64 + i * 16 + l4 * 4;
        if (isV) {
          int g = (n - DMODEL - NKV) >> 7;
          int b = mbase >> 11, s0 = mbase & (SEQ - 1);
          u16_t o[4];
#pragma unroll
          for (int r = 0; r < 4; ++r) o[r] = f2bf(acc[i][j][r] + bs);
          uint2 pk;
          pk.x = (u32_t)o[0] | ((u32_t)o[1] << 16);
          pk.y = (u32_t)o[2] | ((u32_t)o[3] << 16);
          *(uint2*)(Vt + ((size_t)(b * NGRP + g) * HDIM + d) * SEQ + s0) = pk;
        } else {
#pragma unroll
          for (int r = 0; r < 4; ++r) {
            int m = mbase + r;
            int b = m >> 11, s = m & (SEQ - 1);
            float val = acc[i][j][r] + bs;
            float pv = __shfl_xor(val, 1);
            float c = cosT[s * (HDIM / 2) + p];
            float sn = sinT[s * (HDIM / 2) + p];
            float outv = evn ? (val * c - pv * sn) : (pv * sn + val * c);
            if (isK) {
              int g = (n - DMODEL) >> 7;
              Kb[((size_t)(b * NGRP + g) * SEQ + s) * HDIM + d] = f2bf(outv);
            } else {
              int h = n >> 7;
              Qb[((size_t)(b * NHEAD + h) * SEQ + s) * HDIM + d] = f2bf(outv * QSCALE_LOG2E);
            }
          }
        }
      }
    }
  }
}

// ---------------- flash attention (unchanged from round 11/12) ----------------

__global__ __launch_bounds__(256, 2) void k_attn(
    const u16_t* __restrict__ Qb, const u16_t* __restrict__ Kb, const u16_t* __restrict__ Vt,
    u16_t* __restrict__ attn_out) {
  __shared__ u16_t lds[32768];   // K0,K1,V0,V1: 8192 u16 each

  int tid = threadIdx.x, wid = tid >> 6, lane = tid & 63;
  int l15 = lane & 15, l4 = lane >> 4;
  int bh = blockIdx.y;
  int b = bh >> 4, h = bh & 15, g = h >> 2;
  int q0 = blockIdx.x * 128;
  const u16_t* Qhead = Qb + (size_t)(b * NHEAD + h) * SEQ * HDIM;
  const u16_t* Khead = Kb + (size_t)(b * NGRP + g) * SEQ * HDIM;
  const u16_t* Vhead = Vt + (size_t)(b * NGRP + g) * HDIM * SEQ;

  bf16x8 qfa[4], qfb[4];
#pragma unroll
  for (int kc = 0; kc < 4; ++kc) {
    qfa[kc] = *(const bf16x8*)(Qhead + (size_t)(q0 + wid * 32 + l15) * HDIM + kc * 32 + l4 * 8);
    qfb[kc] = *(const bf16x8*)(Qhead + (size_t)(q0 + wid * 32 + 16 + l15) * HDIM + kc * 32 + l4 * 8);
  }

  f32x4 oa[8] = {}, ob[8] = {};
  float la = 0.f, lb = 0.f;

  auto stage = [&](int kv0, int bufIdx) {
    u16_t* Kl = lds + bufIdx * 8192;
    u16_t* Vl = lds + 16384 + bufIdx * 8192;
#pragma unroll
    for (int ss = 0; ss < 4; ++ss) {
      int slot = tid + ss * 256;
      int rK = slot >> 4;
      int cK = (slot & 15) ^ ((rK & 3) | (((rK >> 3) & 1) << 2));
      __builtin_amdgcn_global_load_lds(
          (const __attribute__((address_space(1))) u32_t*)(Khead + (size_t)(kv0 + rK) * HDIM + cK * 8),
          (__attribute__((address_space(3))) u32_t*)(Kl + slot * 8), 16, 0, 0);
      int rV = slot >> 3, cV = (slot & 7) ^ (rV & 7);
      __builtin_amdgcn_global_load_lds(
          (const __attribute__((address_space(1))) u32_t*)(Vhead + (size_t)rV * SEQ + kv0 + cV * 8),
          (__attribute__((address_space(3))) u32_t*)(Vl + slot * 8), 16, 0, 0);
    }
  };

  auto qk = [&](int bufIdx, f32x4 (&Sa)[4], f32x4 (&Sb)[4]) {
    const u16_t* Kcur = lds + bufIdx * 8192;
#pragma unroll
    for (int kc = 0; kc < 4; ++kc) {
#pragma unroll
      for (int kvb = 0; kvb < 4; ++kvb) {
        int row = (l15 >> 2) * 8 + ((kvb & 1) << 2) + (l15 & 3) + ((kvb >> 1) << 5);
        int chunk = ((kc << 2) + l4) ^ (l15 & 7);
        bf16x8 kf = *(const bf16x8*)(Kcur + row * 128 + chunk * 8);
        Sa[kvb] = __builtin_amdgcn_mfma_f32_16x16x32_bf16(kf, qfa[kc], Sa[kvb], 0, 0, 0);
        Sb[kvb] = __builtin_amdgcn_mfma_f32_16x16x32_bf16(kf, qfb[kc], Sb[kvb], 0, 0, 0);
      }
    }
  };

  auto expand = [&](f32x4 (&Sa)[4], f32x4 (&Sb)[4], bf16x8 (&pfa)[2], bf16x8 (&pfb)[2]) {
    bf16x4 pa[4], pb[4];
#pragma unroll
    for (int kvb = 0; kvb < 4; ++kvb) {
#pragma unroll
      for (int r = 0; r < 4; ++r) {
        float ea = __builtin_amdgcn_exp2f(Sa[kvb][r]);
        float eb = __builtin_amdgcn_exp2f(Sb[kvb][r]);
        la += ea; lb += eb;
        pa[kvb][r] = (__bf16)ea;
        pb[kvb][r] = (__bf16)eb;
      }
    }
#pragma unroll
    for (int kc2 = 0; kc2 < 2; ++kc2) {
      uint2 alo = __builtin_bit_cast(uint2, pa[kc2 * 2]);
      uint2 ahi = __builtin_bit_cast(uint2, pa[kc2 * 2 + 1]);
      uint4 wa; wa.x = alo.x; wa.y = alo.y; wa.z = ahi.x; wa.w = ahi.y;
      pfa[kc2] = __builtin_bit_cast(bf16x8, wa);
      uint2 blo = __builtin_bit_cast(uint2, pb[kc2 * 2]);
      uint2 bhi = __builtin_bit_cast(uint2, pb[kc2 * 2 + 1]);
      uint4 wb; wb.x = blo.x; wb.y = blo.y; wb.z = bhi.x; wb.w = bhi.y;
      pfb[kc2] = __builtin_bit_cast(bf16x8, wb);
    }
  };

  auto pv = [&](int bufIdx, bf16x8 (&pfa)[2], bf16x8 (&pfb)[2]) {
    const u16_t* Vcur = lds + 16384 + bufIdx * 8192;
#pragma unroll
    for (int kc2 = 0; kc2 < 2; ++kc2) {
#pragma unroll
      for (int dcb = 0; dcb < 8; ++dcb) {
        int chunk = ((kc2 << 2) + l4) ^ (l15 & 7);
        bf16x8 vf = *(const bf16x8*)(Vcur + (dcb * 16 + l15) * 64 + chunk * 8);
        oa[dcb] = __builtin_amdgcn_mfma_f32_16x16x32_bf16(vf, pfa[kc2], oa[dcb], 0, 0, 0);
        ob[dcb] = __builtin_amdgcn_mfma_f32_16x16x32_bf16(vf, pfb[kc2], ob[dcb], 0, 0, 0);
      }
    }
  };

  auto step = [&](int t, f32x4 (&Ia)[4], f32x4 (&Ib)[4], f32x4 (&Oa)[4], f32x4 (&Ob)[4]) {
    bf16x8 pfa[2], pfb[2];
    expand(Ia, Ib, pfa, pfb);
    asm volatile("s_waitcnt vmcnt(0)" ::: "memory");
    __builtin_amdgcn_s_barrier();
    __builtin_amdgcn_sched_barrier(0);
#pragma unroll
    for (int z = 0; z < 4; ++z)
#pragma unroll
      for (int r = 0; r < 4; ++r) { Oa[z][r] = 0.f; Ob[z][r] = 0.f; }
    __builtin_amdgcn_s_setprio(1);
    pv(t & 1, pfa, pfb);
    qk((t + 1) & 1, Oa, Ob);
    __builtin_amdgcn_s_setprio(0);
    __builtin_amdgcn_sched_barrier(0);
    __builtin_amdgcn_s_barrier();
    __builtin_amdgcn_sched_barrier(0);
    if (t + 2 < SEQ / 64) stage((t + 2) * 64, t & 1);
  };

  f32x4 sA[4] = {}, sB[4] = {}, tA[4], tB[4];

  stage(0, 0);
  stage(64, 1);
  asm volatile("s_waitcnt vmcnt(8)" ::: "memory");
  __builtin_amdgcn_s_barrier();
  __builtin_amdgcn_sched_barrier(0);
  qk(0, sA, sB);

  for (int p = 0; p < 15; ++p) {
    step(2 * p, sA, sB, tA, tB);
    step(2 * p + 1, tA, tB, sA, sB);
  }
  step(30, sA, sB, tA, tB);
  {
    bf16x8 pfa[2], pfb[2];
    expand(tA, tB, pfa, pfb);
    pv(1, pfa, pfb);
  }

  la += __shfl_xor(la, 16); la += __shfl_xor(la, 32);
  lb += __shfl_xor(lb, 16); lb += __shfl_xor(lb, 32);
  float inva = 1.0f / la, invb = 1.0f / lb;

#pragma unroll
  for (int half = 0; half < 2; ++half) {
    u16_t* Owave = lds + half * 8704 + wid * 2176;
    const f32x4* oacc = half ? ob : oa;
    float inv = half ? invb : inva;
#pragma unroll
    for (int dcb = 0; dcb < 8; ++dcb) {
      bf16x4 ov;
#pragma unroll
      for (int r = 0; r < 4; ++r) ov[r] = (__bf16)(oacc[dcb][r] * inv);
      *(uint2*)(Owave + l15 * 136 + dcb * 16 + l4 * 4) = __builtin_bit_cast(uint2, ov);
    }
#pragma unroll
    for (int pass = 0; pass < 4; ++pass) {
      int rowq = pass * 4 + l4;
      int4 v = *(const int4*)(Owave + rowq * 136 + l15 * 8);
      int s = q0 + wid * 32 + half * 16 + rowq;
      *(int4*)(attn_out + ((size_t)(b * SEQ + s)) * DMODEL + h * HDIM + l15 * 8) = v;
    }
  }
}

// ---------------- launcher ----------------

extern "C" void kernel_launch(void* const* d_in, const int* in_sizes, int n_in,
                              void* d_out, int out_size, void* d_ws, size_t ws_size,
                              hipStream_t stream) {
  (void)in_sizes; (void)n_in; (void)out_size; (void)ws_size;
  const float* x  = (const float*)d_in[0];
  const float* rf = (const float*)d_in[1];
  const float* Wq = (const float*)d_in[2];
  const float* bq = (const float*)d_in[3];
  const float* Wk = (const float*)d_in[4];
  const float* bk = (const float*)d_in[5];
  const float* Wv = (const float*)d_in[6];
  const float* bv = (const float*)d_in[7];
  const float* Wo = (const float*)d_in[8];
  const float* bo = (const float*)d_in[9];
  float* out = (float*)d_out;

  char* ws = (char*)d_ws;
  u16_t* xb    = (u16_t*)ws;  ws += (size_t)MROWS * DMODEL * 2;
  u16_t* Wqkvt = (u16_t*)ws;  ws += (size_t)NQKV * DMODEL * 2;
  u16_t* Wot   = (u16_t*)ws;  ws += (size_t)DMODEL * DMODEL * 2;
  float* bqkv  = (float*)ws;  ws += (size_t)NQKV * 4;
  float* cosT  = (float*)ws;  ws += (size_t)SEQ * (HDIM / 2) * 4;
  float* sinT  = (float*)ws;  ws += (size_t)SEQ * (HDIM / 2) * 4;
  u16_t* Qb    = (u16_t*)ws;  ws += (size_t)NB * NHEAD * SEQ * HDIM * 2;
  u16_t* Kb    = (u16_t*)ws;  ws += (size_t)NB * NGRP * SEQ * HDIM * 2;
  u16_t* Vt    = (u16_t*)ws;  ws += (size_t)NB * NGRP * HDIM * SEQ * 2;
  u16_t* attn  = xb;  // alias: xb dead after GEMM1 (strict stream ordering)

  k_cast_x<<<MROWS * DMODEL / 1024, 256, 0, stream>>>(x, xb);
  k_tables<<<SEQ * (HDIM / 2) / 256, 256, 0, stream>>>(rf, cosT, sinT);
  k_bias<<<NQKV / 256, 256, 0, stream>>>(bq, bk, bv, bqkv);

  dim3 tgq(DMODEL / 64, DMODEL / 64);
  dim3 tgk(NKV / 64, DMODEL / 64);
  k_transpose_cast<<<tgq, 256, 0, stream>>>(Wq, DMODEL, Wqkvt, DMODEL);
  k_transpose_cast<<<tgk, 256, 0, stream>>>(Wk, NKV, Wqkvt + (size_t)DMODEL * DMODEL, DMODEL);
  k_transpose_cast<<<tgk, 256, 0, stream>>>(Wv, NKV, Wqkvt + (size_t)(DMODEL + NKV) * DMODEL, DMODEL);
  k_transpose_cast<<<tgq, 256, 0, stream>>>(Wo, DMODEL, Wot, DMODEL);

  // GEMM1: 4096 x 3072 x 2048
  k_gemm<1><<<dim3(NQKV / 128, MROWS / 128), 256, 0, stream>>>(
      xb, Wqkvt, bqkv, nullptr, Qb, Kb, Vt, cosT, sinT, MROWS, NQKV, DMODEL);

  dim3 ga(SEQ / 128, NB * NHEAD);
  k_attn<<<ga, 256, 0, stream>>>(Qb, Kb, Vt, attn);

  // GEMM2: 4096 x 2048 x 2048
  k_gemm<0><<<dim3(DMODEL / 128, MROWS / 128), 256, 0, stream>>>(
      attn, Wot, bo, out, nullptr, nullptr, nullptr, nullptr, nullptr, MROWS, DMODEL, DMODEL);
}

// Round 14
// 205.396 us; speedup vs baseline: 1.0058x; 1.0058x over previous
//
#include <hip/hip_runtime.h>
#include <cstdint>
#include <cstddef>

#define NB 2
#define SEQ 2048
#define DMODEL 2048
#define NHEAD 16
#define HDIM 128
#define NGRP 4
#define NKV (NGRP * HDIM)          // 512
#define NQKV (DMODEL + 2 * NKV)    // 3072
#define MROWS (NB * SEQ)           // 4096
// 1/sqrt(128) * log2(e): Q pre-scale so softmax uses exp2 directly
#define QSCALE_LOG2E 0.12751743f

typedef unsigned short u16_t;
typedef unsigned int u32_t;
typedef __bf16 bf16x8 __attribute__((ext_vector_type(8)));
typedef __bf16 bf16x4 __attribute__((ext_vector_type(4)));
typedef float f32x4 __attribute__((ext_vector_type(4)));

static __device__ __forceinline__ u16_t f2bf(float f) {
  u32_t u = __builtin_bit_cast(u32_t, f);
  u32_t r = u + 0x7FFFu + ((u >> 16) & 1u);
  return (u16_t)(r >> 16);
}

// ---------------- prep kernels ----------------

__global__ void k_cast_x(const float* __restrict__ x, u16_t* __restrict__ xb) {
  int i = blockIdx.x * 256 + threadIdx.x;          // group of 4 floats
  float4 v = ((const float4*)x)[i];
  uint2 pk;
  pk.x = (u32_t)f2bf(v.x) | ((u32_t)f2bf(v.y) << 16);
  pk.y = (u32_t)f2bf(v.z) | ((u32_t)f2bf(v.w) << 16);
  ((uint2*)xb)[i] = pk;
}

__global__ void k_tables(const float* __restrict__ rf, float* __restrict__ cosT,
                         float* __restrict__ sinT) {
  int i = blockIdx.x * 256 + threadIdx.x;          // < SEQ*HDIM/2
  float f = rf[i];
  cosT[i] = cosf(f);
  sinT[i] = sinf(f);
}

__global__ void k_bias(const float* __restrict__ bq, const float* __restrict__ bk,
                       const float* __restrict__ bv, float* __restrict__ bqkv) {
  int i = blockIdx.x * 256 + threadIdx.x;          // < NQKV
  float v = (i < DMODEL) ? bq[i] : (i < DMODEL + NKV ? bk[i - DMODEL] : bv[i - DMODEL - NKV]);
  bqkv[i] = v;
}

// W: [K][N] fp32 row-major -> Wt: [N][K] bf16 row-major
__global__ void k_transpose_cast(const float* __restrict__ W, int N,
                                 u16_t* __restrict__ Wt, int K) {
  __shared__ float tile[64][65];
  int n0 = blockIdx.x * 64, k0 = blockIdx.y * 64;
  int t = threadIdx.x;
#pragma unroll
  for (int pass = 0; pass < 4; ++pass) {
    int slot = pass * 256 + t;
    int r = slot >> 4, c4 = (slot & 15) * 4;
    float4 v = *(const float4*)(W + (size_t)(k0 + r) * N + n0 + c4);
    tile[r][c4] = v.x; tile[r][c4 + 1] = v.y; tile[r][c4 + 2] = v.z; tile[r][c4 + 3] = v.w;
  }
  __syncthreads();
  int nr = t >> 2, seg = t & 3;
  alignas(16) u16_t o[16];
#pragma unroll
  for (int kk = 0; kk < 16; ++kk) o[kk] = f2bf(tile[seg * 16 + kk][nr]);
  u16_t* dst = Wt + (size_t)(n0 + nr) * K + k0 + seg * 16;
  ((int4*)dst)[0] = ((const int4*)o)[0];
  ((int4*)dst)[1] = ((const int4*)o)[1];
}

// ---------------- GEMM: C[M][N] = A[M][K](bf16) * Bt[N][K](bf16)^T + bias ----------
// Round-14: 128x128 tile, BK=32, but 512 threads / 8 WAVES (wave = 64x32 output,
// acc[4][2]) -> 24 waves/CU at 3 blocks/CU (was 12) to attack the latency slack
// (R13 counters: MfmaUtil 25, VALUBusy 20, Occupancy 30% grid-capped).
// Ledger = R11's proven form, verbatim: prologue stage(0),stage(1);
//   region t: vmcnt(2) [stage=2 VMEM instr/wave now] -> bar#1 -> rdfrags(t)+MFMA(t)
//             -> bar#2 -> stage(t+2) into slot t&1.
// 2-slot LDS (32KB), plain 2D grid, source-preswizzled chunks (c^=row&3).
// __launch_bounds__(512,6): 6 waves/EU = 3 blocks/CU target, VGPR cap 85.
// EPI 0: fp32 out.  EPI 1: QKV epilogue (RoPE, Q pre-scaled, V transposed).

template <int EPI>
__global__ __launch_bounds__(512, 6) void k_gemm(
    const u16_t* __restrict__ A, const u16_t* __restrict__ Bt, const float* __restrict__ bias,
    float* __restrict__ Cout, u16_t* __restrict__ Qb, u16_t* __restrict__ Kb,
    u16_t* __restrict__ Vt, const float* __restrict__ cosT, const float* __restrict__ sinT,
    int M, int N, int K) {
  // u16: A slot0 [0,4096), A slot1 [4096,8192), B slot0 [8192,12288), B slot1 [12288,16384)
  __shared__ u16_t lds[16384];
  int tid = threadIdx.x;
  int wid = tid >> 6, lane = tid & 63;
  int l15 = lane & 15, l4 = lane >> 4;
  int wrow = wid >> 2, wcol = wid & 3;     // 2 x 4 wave grid; wave owns 64x32

  int m0 = blockIdx.y << 7, n0 = blockIdx.x << 7;

  f32x4 acc[4][2] = {};

  // stage K-tile t into slot (t&1): A[128][32], B[128][32]; 16B chunks, source
  // pre-swizzled c' = c ^ (row&3). 2 VMEM instr per thread (1 A + 1 B).
  auto stage = [&](int t) {
    u16_t* Al = lds + (t & 1) * 4096;
    u16_t* Bl = lds + 8192 + (t & 1) * 4096;
    int kbase = t * 32;
    int row = tid >> 2, c = tid & 3;
    int cs = c ^ (row & 3);
    __builtin_amdgcn_global_load_lds(
        (const __attribute__((address_space(1))) u32_t*)(A + (size_t)(m0 + row) * K + kbase + cs * 8),
        (__attribute__((address_space(3))) u32_t*)(Al + tid * 8), 16, 0, 0);
    __builtin_amdgcn_global_load_lds(
        (const __attribute__((address_space(1))) u32_t*)(Bt + (size_t)(n0 + row) * K + kbase + cs * 8),
        (__attribute__((address_space(3))) u32_t*)(Bl + tid * 8), 16, 0, 0);
  };

  stage(0);
  stage(1);

  const int NT = K >> 5;   // 64
  for (int t = 0; t < NT; ++t) {
    if (t == NT - 1) {
      asm volatile("s_waitcnt vmcnt(0)" ::: "memory");
    } else {
      asm volatile("s_waitcnt vmcnt(2)" ::: "memory");   // tile t landed; t+1 in flight
    }
    __builtin_amdgcn_s_barrier();                        // #1: slot (t&1) valid
    __builtin_amdgcn_sched_barrier(0);

    const u16_t* Acur = lds + (t & 1) * 4096;
    const u16_t* Bcur = lds + 8192 + (t & 1) * 4096;

    int chunk = l4 ^ (l15 & 3);                          // swizzled k-chunk
    bf16x8 af[4], bfr[2];
#pragma unroll
    for (int i = 0; i < 4; ++i)
      af[i] = *(const bf16x8*)(Acur + (wrow * 64 + i * 16 + l15) * 32 + chunk * 8);
#pragma unroll
    for (int j = 0; j < 2; ++j)
      bfr[j] = *(const bf16x8*)(Bcur + (wcol * 32 + j * 16 + l15) * 32 + chunk * 8);

    __builtin_amdgcn_s_setprio(1);
#pragma unroll
    for (int i = 0; i < 4; ++i)
#pragma unroll
      for (int j = 0; j < 2; ++j)
        acc[i][j] = __builtin_amdgcn_mfma_f32_16x16x32_bf16(af[i], bfr[j], acc[i][j], 0, 0, 0);
    __builtin_amdgcn_s_setprio(0);

    __builtin_amdgcn_sched_barrier(0);
    __builtin_amdgcn_s_barrier();                        // #2: slot (t&1) free
    __builtin_amdgcn_sched_barrier(0);
    if (t + 2 < NT) stage(t + 2);                        // into slot (t&1)
  }

  if (EPI == 0) {
#pragma unroll
    for (int j = 0; j < 2; ++j) {
      int n = n0 + wcol * 32 + j * 16 + l15;
      float bs = bias[n];
#pragma unroll
      for (int i = 0; i < 4; ++i) {
        int mbase = m0 + wrow * 64 + i * 16 + l4 * 4;
#pragma unroll
        for (int r = 0; r < 4; ++r)
          Cout[(size_t)(mbase + r) * N + n] = acc[i][j][r] + bs;
      }
    }
  } else {
    bool isV = (n0 >= DMODEL + NKV);
    bool isK = (n0 >= DMODEL) && !isV;
#pragma unroll
    for (int j = 0; j < 2; ++j) {
      int n = n0 + wcol * 32 + j * 16 + l15;
      float bs = bias[n];
      int d = n & (HDIM - 1);
      int p = d >> 1;
      bool evn = !(d & 1);
#pragma unroll
      for (int i = 0; i < 4; ++i) {
        int mbase = m0 + wrow * 64 + i * 16 + l4 * 4;
        if (isV) {
          int g = (n - DMODEL - NKV) >> 7;
          int b = mbase >> 11, s0 = mbase & (SEQ - 1);
          u16_t o[4];
#pragma unroll
          for (int r = 0; r < 4; ++r) o[r] = f2bf(acc[i][j][r] + bs);
          uint2 pk;
          pk.x = (u32_t)o[0] | ((u32_t)o[1] << 16);
          pk.y = (u32_t)o[2] | ((u32_t)o[3] << 16);
          *(uint2*)(Vt + ((size_t)(b * NGRP + g) * HDIM + d) * SEQ + s0) = pk;
        } else {
#pragma unroll
          for (int r = 0; r < 4; ++r) {
            int m = mbase + r;
            int b = m >> 11, s = m & (SEQ - 1);
            float val = acc[i][j][r] + bs;
            float pv = __shfl_xor(val, 1);
            float c = cosT[s * (HDIM / 2) + p];
            float sn = sinT[s * (HDIM / 2) + p];
            float outv = evn ? (val * c - pv * sn) : (pv * sn + val * c);
            if (isK) {
              int g = (n - DMODEL) >> 7;
              Kb[((size_t)(b * NGRP + g) * SEQ + s) * HDIM + d] = f2bf(outv);
            } else {
              int h = n >> 7;
              Qb[((size_t)(b * NHEAD + h) * SEQ + s) * HDIM + d] = f2bf(outv * QSCALE_LOG2E);
            }
          }
        }
      }
    }
  }
}

// ---------------- flash attention (unchanged from round 11/12/13) ----------------

__global__ __launch_bounds__(256, 2) void k_attn(
    const u16_t* __restrict__ Qb, const u16_t* __restrict__ Kb, const u16_t* __restrict__ Vt,
    u16_t* __restrict__ attn_out) {
  __shared__ u16_t lds[32768];   // K0,K1,V0,V1: 8192 u16 each

  int tid = threadIdx.x, wid = tid >> 6, lane = tid & 63;
  int l15 = lane & 15, l4 = lane >> 4;
  int bh = blockIdx.y;
  int b = bh >> 4, h = bh & 15, g = h >> 2;
  int q0 = blockIdx.x * 128;
  const u16_t* Qhead = Qb + (size_t)(b * NHEAD + h) * SEQ * HDIM;
  const u16_t* Khead = Kb + (size_t)(b * NGRP + g) * SEQ * HDIM;
  const u16_t* Vhead = Vt + (size_t)(b * NGRP + g) * HDIM * SEQ;

  bf16x8 qfa[4], qfb[4];
#pragma unroll
  for (int kc = 0; kc < 4; ++kc) {
    qfa[kc] = *(const bf16x8*)(Qhead + (size_t)(q0 + wid * 32 + l15) * HDIM + kc * 32 + l4 * 8);
    qfb[kc] = *(const bf16x8*)(Qhead + (size_t)(q0 + wid * 32 + 16 + l15) * HDIM + kc * 32 + l4 * 8);
  }

  f32x4 oa[8] = {}, ob[8] = {};
  float la = 0.f, lb = 0.f;

  auto stage = [&](int kv0, int bufIdx) {
    u16_t* Kl = lds + bufIdx * 8192;
    u16_t* Vl = lds + 16384 + bufIdx * 8192;
#pragma unroll
    for (int ss = 0; ss < 4; ++ss) {
      int slot = tid + ss * 256;
      int rK = slot >> 4;
      int cK = (slot & 15) ^ ((rK & 3) | (((rK >> 3) & 1) << 2));
      __builtin_amdgcn_global_load_lds(
          (const __attribute__((address_space(1))) u32_t*)(Khead + (size_t)(kv0 + rK) * HDIM + cK * 8),
          (__attribute__((address_space(3))) u32_t*)(Kl + slot * 8), 16, 0, 0);
      int rV = slot >> 3, cV = (slot & 7) ^ (rV & 7);
      __builtin_amdgcn_global_load_lds(
          (const __attribute__((address_space(1))) u32_t*)(Vhead + (size_t)rV * SEQ + kv0 + cV * 8),
          (__attribute__((address_space(3))) u32_t*)(Vl + slot * 8), 16, 0, 0);
    }
  };

  auto qk = [&](int bufIdx, f32x4 (&Sa)[4], f32x4 (&Sb)[4]) {
    const u16_t* Kcur = lds + bufIdx * 8192;
#pragma unroll
    for (int kc = 0; kc < 4; ++kc) {
#pragma unroll
      for (int kvb = 0; kvb < 4; ++kvb) {
        int row = (l15 >> 2) * 8 + ((kvb & 1) << 2) + (l15 & 3) + ((kvb >> 1) << 5);
        int chunk = ((kc << 2) + l4) ^ (l15 & 7);
        bf16x8 kf = *(const bf16x8*)(Kcur + row * 128 + chunk * 8);
        Sa[kvb] = __builtin_amdgcn_mfma_f32_16x16x32_bf16(kf, qfa[kc], Sa[kvb], 0, 0, 0);
        Sb[kvb] = __builtin_amdgcn_mfma_f32_16x16x32_bf16(kf, qfb[kc], Sb[kvb], 0, 0, 0);
      }
    }
  };

  auto expand = [&](f32x4 (&Sa)[4], f32x4 (&Sb)[4], bf16x8 (&pfa)[2], bf16x8 (&pfb)[2]) {
    bf16x4 pa[4], pb[4];
#pragma unroll
    for (int kvb = 0; kvb < 4; ++kvb) {
#pragma unroll
      for (int r = 0; r < 4; ++r) {
        float ea = __builtin_amdgcn_exp2f(Sa[kvb][r]);
        float eb = __builtin_amdgcn_exp2f(Sb[kvb][r]);
        la += ea; lb += eb;
        pa[kvb][r] = (__bf16)ea;
        pb[kvb][r] = (__bf16)eb;
      }
    }
#pragma unroll
    for (int kc2 = 0; kc2 < 2; ++kc2) {
      uint2 alo = __builtin_bit_cast(uint2, pa[kc2 * 2]);
      uint2 ahi = __builtin_bit_cast(uint2, pa[kc2 * 2 + 1]);
      uint4 wa; wa.x = alo.x; wa.y = alo.y; wa.z = ahi.x; wa.w = ahi.y;
      pfa[kc2] = __builtin_bit_cast(bf16x8, wa);
      uint2 blo = __builtin_bit_cast(uint2, pb[kc2 * 2]);
      uint2 bhi = __builtin_bit_cast(uint2, pb[kc2 * 2 + 1]);
      uint4 wb; wb.x = blo.x; wb.y = blo.y; wb.z = bhi.x; wb.w = bhi.y;
      pfb[kc2] = __builtin_bit_cast(bf16x8, wb);
    }
  };

  auto pv = [&](int bufIdx, bf16x8 (&pfa)[2], bf16x8 (&pfb)[2]) {
    const u16_t* Vcur = lds + 16384 + bufIdx * 8192;
#pragma unroll
    for (int kc2 = 0; kc2 < 2; ++kc2) {
#pragma unroll
      for (int dcb = 0; dcb < 8; ++dcb) {
        int chunk = ((kc2 << 2) + l4) ^ (l15 & 7);
        bf16x8 vf = *(const bf16x8*)(Vcur + (dcb * 16 + l15) * 64 + chunk * 8);
        oa[dcb] = __builtin_amdgcn_mfma_f32_16x16x32_bf16(vf, pfa[kc2], oa[dcb], 0, 0, 0);
        ob[dcb] = __builtin_amdgcn_mfma_f32_16x16x32_bf16(vf, pfb[kc2], ob[dcb], 0, 0, 0);
      }
    }
  };

  auto step = [&](int t, f32x4 (&Ia)[4], f32x4 (&Ib)[4], f32x4 (&Oa)[4], f32x4 (&Ob)[4]) {
    bf16x8 pfa[2], pfb[2];
    expand(Ia, Ib, pfa, pfb);
    asm volatile("s_waitcnt vmcnt(0)" ::: "memory");
    __builtin_amdgcn_s_barrier();
    __builtin_amdgcn_sched_barrier(0);
#pragma unroll
    for (int z = 0; z < 4; ++z)
#pragma unroll
      for (int r = 0; r < 4; ++r) { Oa[z][r] = 0.f; Ob[z][r] = 0.f; }
    __builtin_amdgcn_s_setprio(1);
    pv(t & 1, pfa, pfb);
    qk((t + 1) & 1, Oa, Ob);
    __builtin_amdgcn_s_setprio(0);
    __builtin_amdgcn_sched_barrier(0);
    __builtin_amdgcn_s_barrier();
    __builtin_amdgcn_sched_barrier(0);
    if (t + 2 < SEQ / 64) stage((t + 2) * 64, t & 1);
  };

  f32x4 sA[4] = {}, sB[4] = {}, tA[4], tB[4];

  stage(0, 0);
  stage(64, 1);
  asm volatile("s_waitcnt vmcnt(8)" ::: "memory");
  __builtin_amdgcn_s_barrier();
  __builtin_amdgcn_sched_barrier(0);
  qk(0, sA, sB);

  for (int p = 0; p < 15; ++p) {
    step(2 * p, sA, sB, tA, tB);
    step(2 * p + 1, tA, tB, sA, sB);
  }
  step(30, sA, sB, tA, tB);
  {
    bf16x8 pfa[2], pfb[2];
    expand(tA, tB, pfa, pfb);
    pv(1, pfa, pfb);
  }

  la += __shfl_xor(la, 16); la += __shfl_xor(la, 32);
  lb += __shfl_xor(lb, 16); lb += __shfl_xor(lb, 32);
  float inva = 1.0f / la, invb = 1.0f / lb;

#pragma unroll
  for (int half = 0; half < 2; ++half) {
    u16_t* Owave = lds + half * 8704 + wid * 2176;
    const f32x4* oacc = half ? ob : oa;
    float inv = half ? invb : inva;
#pragma unroll
    for (int dcb = 0; dcb < 8; ++dcb) {
      bf16x4 ov;
#pragma unroll
      for (int r = 0; r < 4; ++r) ov[r] = (__bf16)(oacc[dcb][r] * inv);
      *(uint2*)(Owave + l15 * 136 + dcb * 16 + l4 * 4) = __builtin_bit_cast(uint2, ov);
    }
#pragma unroll
    for (int pass = 0; pass < 4; ++pass) {
      int rowq = pass * 4 + l4;
      int4 v = *(const int4*)(Owave + rowq * 136 + l15 * 8);
      int s = q0 + wid * 32 + half * 16 + rowq;
      *(int4*)(attn_out + ((size_t)(b * SEQ + s)) * DMODEL + h * HDIM + l15 * 8) = v;
    }
  }
}

// ---------------- launcher ----------------

extern "C" void kernel_launch(void* const* d_in, const int* in_sizes, int n_in,
                              void* d_out, int out_size, void* d_ws, size_t ws_size,
                              hipStream_t stream) {
  (void)in_sizes; (void)n_in; (void)out_size; (void)ws_size;
  const float* x  = (const float*)d_in[0];
  const float* rf = (const float*)d_in[1];
  const float* Wq = (const float*)d_in[2];
  const float* bq = (const float*)d_in[3];
  const float* Wk = (const float*)d_in[4];
  const float* bk = (const float*)d_in[5];
  const float* Wv = (const float*)d_in[6];
  const float* bv = (const float*)d_in[7];
  const float* Wo = (const float*)d_in[8];
  const float* bo = (const float*)d_in[9];
  float* out = (float*)d_out;

  char* ws = (char*)d_ws;
  u16_t* xb    = (u16_t*)ws;  ws += (size_t)MROWS * DMODEL * 2;
  u16_t* Wqkvt = (u16_t*)ws;  ws += (size_t)NQKV * DMODEL * 2;
  u16_t* Wot   = (u16_t*)ws;  ws += (size_t)DMODEL * DMODEL * 2;
  float* bqkv  = (float*)ws;  ws += (size_t)NQKV * 4;
  float* cosT  = (float*)ws;  ws += (size_t)SEQ * (HDIM / 2) * 4;
  float* sinT  = (float*)ws;  ws += (size_t)SEQ * (HDIM / 2) * 4;
  u16_t* Qb    = (u16_t*)ws;  ws += (size_t)NB * NHEAD * SEQ * HDIM * 2;
  u16_t* Kb    = (u16_t*)ws;  ws += (size_t)NB * NGRP * SEQ * HDIM * 2;
  u16_t* Vt    = (u16_t*)ws;  ws += (size_t)NB * NGRP * HDIM * SEQ * 2;
  u16_t* attn  = xb;  // alias: xb dead after GEMM1 (strict stream ordering)

  k_cast_x<<<MROWS * DMODEL / 1024, 256, 0, stream>>>(x, xb);
  k_tables<<<SEQ * (HDIM / 2) / 256, 256, 0, stream>>>(rf, cosT, sinT);
  k_bias<<<NQKV / 256, 256, 0, stream>>>(bq, bk, bv, bqkv);

  dim3 tgq(DMODEL / 64, DMODEL / 64);
  dim3 tgk(NKV / 64, DMODEL / 64);
  k_transpose_cast<<<tgq, 256, 0, stream>>>(Wq, DMODEL, Wqkvt, DMODEL);
  k_transpose_cast<<<tgk, 256, 0, stream>>>(Wk, NKV, Wqkvt + (size_t)DMODEL * DMODEL, DMODEL);
  k_transpose_cast<<<tgk, 256, 0, stream>>>(Wv, NKV, Wqkvt + (size_t)(DMODEL + NKV) * DMODEL, DMODEL);
  k_transpose_cast<<<tgq, 256, 0, stream>>>(Wo, DMODEL, Wot, DMODEL);

  // GEMM1: 4096 x 3072 x 2048, 512-thread blocks
  k_gemm<1><<<dim3(NQKV / 128, MROWS / 128), 512, 0, stream>>>(
      xb, Wqkvt, bqkv, nullptr, Qb, Kb, Vt, cosT, sinT, MROWS, NQKV, DMODEL);

  dim3 ga(SEQ / 128, NB * NHEAD);
  k_attn<<<ga, 256, 0, stream>>>(Qb, Kb, Vt, attn);

  // GEMM2: 4096 x 2048 x 2048, 512-thread blocks
  k_gemm<0><<<dim3(DMODEL / 128, MROWS / 128), 512, 0, stream>>>(
      attn, Wot, bo, out, nullptr, nullptr, nullptr, nullptr, nullptr, MROWS, DMODEL, DMODEL);
}

// Round 15
// 186.702 us; speedup vs baseline: 1.1066x; 1.1001x over previous
//
#include <hip/hip_runtime.h>
#include <cstdint>
#include <cstddef>

#define NB 2
#define SEQ 2048
#define DMODEL 2048
#define NHEAD 16
#define HDIM 128
#define NGRP 4
#define NKV (NGRP * HDIM)          // 512
#define NQKV (DMODEL + 2 * NKV)    // 3072
#define MROWS (NB * SEQ)           // 4096
// 1/sqrt(128) * log2(e): Q pre-scale so softmax uses exp2 directly
#define QSCALE_LOG2E 0.12751743f

typedef unsigned short u16_t;
typedef unsigned int u32_t;
typedef __bf16 bf16x8 __attribute__((ext_vector_type(8)));
typedef __bf16 bf16x4 __attribute__((ext_vector_type(4)));
typedef float f32x4 __attribute__((ext_vector_type(4)));

static __device__ __forceinline__ u16_t f2bf(float f) {
  u32_t u = __builtin_bit_cast(u32_t, f);
  u32_t r = u + 0x7FFFu + ((u >> 16) & 1u);
  return (u16_t)(r >> 16);
}

// ---------------- prep kernels ----------------

__global__ void k_cast_x(const float* __restrict__ x, u16_t* __restrict__ xb) {
  int i = blockIdx.x * 256 + threadIdx.x;          // group of 4 floats
  float4 v = ((const float4*)x)[i];
  uint2 pk;
  pk.x = (u32_t)f2bf(v.x) | ((u32_t)f2bf(v.y) << 16);
  pk.y = (u32_t)f2bf(v.z) | ((u32_t)f2bf(v.w) << 16);
  ((uint2*)xb)[i] = pk;
}

__global__ void k_tables(const float* __restrict__ rf, float* __restrict__ cosT,
                         float* __restrict__ sinT) {
  int i = blockIdx.x * 256 + threadIdx.x;          // < SEQ*HDIM/2
  float f = rf[i];
  cosT[i] = cosf(f);
  sinT[i] = sinf(f);
}

__global__ void k_bias(const float* __restrict__ bq, const float* __restrict__ bk,
                       const float* __restrict__ bv, float* __restrict__ bqkv) {
  int i = blockIdx.x * 256 + threadIdx.x;          // < NQKV
  float v = (i < DMODEL) ? bq[i] : (i < DMODEL + NKV ? bk[i - DMODEL] : bv[i - DMODEL - NKV]);
  bqkv[i] = v;
}

// W: [K][N] fp32 row-major -> Wt: [N][K] bf16 row-major
__global__ void k_transpose_cast(const float* __restrict__ W, int N,
                                 u16_t* __restrict__ Wt, int K) {
  __shared__ float tile[64][65];
  int n0 = blockIdx.x * 64, k0 = blockIdx.y * 64;
  int t = threadIdx.x;
#pragma unroll
  for (int pass = 0; pass < 4; ++pass) {
    int slot = pass * 256 + t;
    int r = slot >> 4, c4 = (slot & 15) * 4;
    float4 v = *(const float4*)(W + (size_t)(k0 + r) * N + n0 + c4);
    tile[r][c4] = v.x; tile[r][c4 + 1] = v.y; tile[r][c4 + 2] = v.z; tile[r][c4 + 3] = v.w;
  }
  __syncthreads();
  int nr = t >> 2, seg = t & 3;
  alignas(16) u16_t o[16];
#pragma unroll
  for (int kk = 0; kk < 16; ++kk) o[kk] = f2bf(tile[seg * 16 + kk][nr]);
  u16_t* dst = Wt + (size_t)(n0 + nr) * K + k0 + seg * 16;
  ((int4*)dst)[0] = ((const int4*)o)[0];
  ((int4*)dst)[1] = ((const int4*)o)[1];
}

// ---------------- GEMM: C[M][N] = A[M][K](bf16) * Bt[N][K](bf16)^T + bias ----------
// Round-15: 128x128 tile, BK=64 (32 regions, was 64): halves per-region fixed
// costs (2 barriers + vmcnt + setprio), doubles the intra-region scheduling
// window (12 ds_reads + 16 MFMA, no barriers inside). 512 threads / 8 waves
// (wave = 64x32, acc[4][2]). Ledger = R11/R14 proven form, constants changed:
//   prologue stage(0), stage(1)   [4 VMEM instr/wave each]
//   region t: vmcnt(4) [tile t landed; t+1 in flight] -> bar#1
//             -> frags+MFMA (kk=0,1) -> bar#2 -> stage(t+2) into slot t&1
// LDS 64KB (2 slots x (A[128][64]+B[128][64])) -> 2 blocks/CU, 16 waves/CU.
// Swizzle widened for 128B rows: source cs = c^(row&7); read chunk ^= l15&7.
// EPI 0: fp32 out.  EPI 1: QKV epilogue (RoPE, Q pre-scaled, V transposed).

template <int EPI>
__global__ __launch_bounds__(512, 4) void k_gemm(
    const u16_t* __restrict__ A, const u16_t* __restrict__ Bt, const float* __restrict__ bias,
    float* __restrict__ Cout, u16_t* __restrict__ Qb, u16_t* __restrict__ Kb,
    u16_t* __restrict__ Vt, const float* __restrict__ cosT, const float* __restrict__ sinT,
    int M, int N, int K) {
  // u16: A0 [0,8192) A1 [8192,16384) B0 [16384,24576) B1 [24576,32768)
  __shared__ u16_t lds[32768];
  int tid = threadIdx.x;
  int wid = tid >> 6, lane = tid & 63;
  int l15 = lane & 15, l4 = lane >> 4;
  int wrow = wid >> 2, wcol = wid & 3;     // 2 x 4 wave grid; wave owns 64x32

  int m0 = blockIdx.y << 7, n0 = blockIdx.x << 7;

  f32x4 acc[4][2] = {};

  // stage K-tile t (BK=64) into slot (t&1): A[128][64], B[128][64]; 16B chunks,
  // source pre-swizzled cs = c ^ (row&7). 4 VMEM instr per thread (2 A + 2 B).
  auto stage = [&](int t) {
    u16_t* Al = lds + (t & 1) * 8192;
    u16_t* Bl = lds + 16384 + (t & 1) * 8192;
    int kbase = t * 64;
#pragma unroll
    for (int ss = 0; ss < 2; ++ss) {
      int slot = tid + ss * 512;           // 0..1023: 128 rows x 8 chunks
      int row = slot >> 3, c = slot & 7;
      int cs = c ^ (row & 7);
      __builtin_amdgcn_global_load_lds(
          (const __attribute__((address_space(1))) u32_t*)(A + (size_t)(m0 + row) * K + kbase + cs * 8),
          (__attribute__((address_space(3))) u32_t*)(Al + slot * 8), 16, 0, 0);
      __builtin_amdgcn_global_load_lds(
          (const __attribute__((address_space(1))) u32_t*)(Bt + (size_t)(n0 + row) * K + kbase + cs * 8),
          (__attribute__((address_space(3))) u32_t*)(Bl + slot * 8), 16, 0, 0);
    }
  };

  stage(0);
  stage(1);

  const int NT = K >> 6;   // 32
  for (int t = 0; t < NT; ++t) {
    if (t == NT - 1) {
      asm volatile("s_waitcnt vmcnt(0)" ::: "memory");
    } else {
      asm volatile("s_waitcnt vmcnt(4)" ::: "memory");   // tile t landed; t+1 in flight
    }
    __builtin_amdgcn_s_barrier();                        // #1: slot (t&1) valid
    __builtin_amdgcn_sched_barrier(0);

    const u16_t* Acur = lds + (t & 1) * 8192;
    const u16_t* Bcur = lds + 16384 + (t & 1) * 8192;

#pragma unroll
    for (int kk = 0; kk < 2; ++kk) {
      int chunk = ((kk << 2) + l4) ^ (l15 & 7);          // swizzled k-chunk
      bf16x8 af[4], bfr[2];
#pragma unroll
      for (int i = 0; i < 4; ++i)
        af[i] = *(const bf16x8*)(Acur + (wrow * 64 + i * 16 + l15) * 64 + chunk * 8);
#pragma unroll
      for (int j = 0; j < 2; ++j)
        bfr[j] = *(const bf16x8*)(Bcur + (wcol * 32 + j * 16 + l15) * 64 + chunk * 8);

      __builtin_amdgcn_s_setprio(1);
#pragma unroll
      for (int i = 0; i < 4; ++i)
#pragma unroll
        for (int j = 0; j < 2; ++j)
          acc[i][j] = __builtin_amdgcn_mfma_f32_16x16x32_bf16(af[i], bfr[j], acc[i][j], 0, 0, 0);
      __builtin_amdgcn_s_setprio(0);
    }

    __builtin_amdgcn_sched_barrier(0);
    __builtin_amdgcn_s_barrier();                        // #2: slot (t&1) free
    __builtin_amdgcn_sched_barrier(0);
    if (t + 2 < NT) stage(t + 2);                        // into slot (t&1)
  }

  if (EPI == 0) {
#pragma unroll
    for (int j = 0; j < 2; ++j) {
      int n = n0 + wcol * 32 + j * 16 + l15;
      float bs = bias[n];
#pragma unroll
      for (int i = 0; i < 4; ++i) {
        int mbase = m0 + wrow * 64 + i * 16 + l4 * 4;
#pragma unroll
        for (int r = 0; r < 4; ++r)
          Cout[(size_t)(mbase + r) * N + n] = acc[i][j][r] + bs;
      }
    }
  } else {
    bool isV = (n0 >= DMODEL + NKV);
    bool isK = (n0 >= DMODEL) && !isV;
#pragma unroll
    for (int j = 0; j < 2; ++j) {
      int n = n0 + wcol * 32 + j * 16 + l15;
      float bs = bias[n];
      int d = n & (HDIM - 1);
      int p = d >> 1;
      bool evn = !(d & 1);
#pragma unroll
      for (int i = 0; i < 4; ++i) {
        int mbase = m0 + wrow * 64 + i * 16 + l4 * 4;
        if (isV) {
          int g = (n - DMODEL - NKV) >> 7;
          int b = mbase >> 11, s0 = mbase & (SEQ - 1);
          u16_t o[4];
#pragma unroll
          for (int r = 0; r < 4; ++r) o[r] = f2bf(acc[i][j][r] + bs);
          uint2 pk;
          pk.x = (u32_t)o[0] | ((u32_t)o[1] << 16);
          pk.y = (u32_t)o[2] | ((u32_t)o[3] << 16);
          *(uint2*)(Vt + ((size_t)(b * NGRP + g) * HDIM + d) * SEQ + s0) = pk;
        } else {
#pragma unroll
          for (int r = 0; r < 4; ++r) {
            int m = mbase + r;
            int b = m >> 11, s = m & (SEQ - 1);
            float val = acc[i][j][r] + bs;
            float pv = __shfl_xor(val, 1);
            float c = cosT[s * (HDIM / 2) + p];
            float sn = sinT[s * (HDIM / 2) + p];
            float outv = evn ? (val * c - pv * sn) : (pv * sn + val * c);
            if (isK) {
              int g = (n - DMODEL) >> 7;
              Kb[((size_t)(b * NGRP + g) * SEQ + s) * HDIM + d] = f2bf(outv);
            } else {
              int h = n >> 7;
              Qb[((size_t)(b * NHEAD + h) * SEQ + s) * HDIM + d] = f2bf(outv * QSCALE_LOG2E);
            }
          }
        }
      }
    }
  }
}

// ---------------- flash attention (unchanged from round 11/12/13/14) ----------------

__global__ __launch_bounds__(256, 2) void k_attn(
    const u16_t* __restrict__ Qb, const u16_t* __restrict__ Kb, const u16_t* __restrict__ Vt,
    u16_t* __restrict__ attn_out) {
  __shared__ u16_t lds[32768];   // K0,K1,V0,V1: 8192 u16 each

  int tid = threadIdx.x, wid = tid >> 6, lane = tid & 63;
  int l15 = lane & 15, l4 = lane >> 4;
  int bh = blockIdx.y;
  int b = bh >> 4, h = bh & 15, g = h >> 2;
  int q0 = blockIdx.x * 128;
  const u16_t* Qhead = Qb + (size_t)(b * NHEAD + h) * SEQ * HDIM;
  const u16_t* Khead = Kb + (size_t)(b * NGRP + g) * SEQ * HDIM;
  const u16_t* Vhead = Vt + (size_t)(b * NGRP + g) * HDIM * SEQ;

  bf16x8 qfa[4], qfb[4];
#pragma unroll
  for (int kc = 0; kc < 4; ++kc) {
    qfa[kc] = *(const bf16x8*)(Qhead + (size_t)(q0 + wid * 32 + l15) * HDIM + kc * 32 + l4 * 8);
    qfb[kc] = *(const bf16x8*)(Qhead + (size_t)(q0 + wid * 32 + 16 + l15) * HDIM + kc * 32 + l4 * 8);
  }

  f32x4 oa[8] = {}, ob[8] = {};
  float la = 0.f, lb = 0.f;

  auto stage = [&](int kv0, int bufIdx) {
    u16_t* Kl = lds + bufIdx * 8192;
    u16_t* Vl = lds + 16384 + bufIdx * 8192;
#pragma unroll
    for (int ss = 0; ss < 4; ++ss) {
      int slot = tid + ss * 256;
      int rK = slot >> 4;
      int cK = (slot & 15) ^ ((rK & 3) | (((rK >> 3) & 1) << 2));
      __builtin_amdgcn_global_load_lds(
          (const __attribute__((address_space(1))) u32_t*)(Khead + (size_t)(kv0 + rK) * HDIM + cK * 8),
          (__attribute__((address_space(3))) u32_t*)(Kl + slot * 8), 16, 0, 0);
      int rV = slot >> 3, cV = (slot & 7) ^ (rV & 7);
      __builtin_amdgcn_global_load_lds(
          (const __attribute__((address_space(1))) u32_t*)(Vhead + (size_t)rV * SEQ + kv0 + cV * 8),
          (__attribute__((address_space(3))) u32_t*)(Vl + slot * 8), 16, 0, 0);
    }
  };

  auto qk = [&](int bufIdx, f32x4 (&Sa)[4], f32x4 (&Sb)[4]) {
    const u16_t* Kcur = lds + bufIdx * 8192;
#pragma unroll
    for (int kc = 0; kc < 4; ++kc) {
#pragma unroll
      for (int kvb = 0; kvb < 4; ++kvb) {
        int row = (l15 >> 2) * 8 + ((kvb & 1) << 2) + (l15 & 3) + ((kvb >> 1) << 5);
        int chunk = ((kc << 2) + l4) ^ (l15 & 7);
        bf16x8 kf = *(const bf16x8*)(Kcur + row * 128 + chunk * 8);
        Sa[kvb] = __builtin_amdgcn_mfma_f32_16x16x32_bf16(kf, qfa[kc], Sa[kvb], 0, 0, 0);
        Sb[kvb] = __builtin_amdgcn_mfma_f32_16x16x32_bf16(kf, qfb[kc], Sb[kvb], 0, 0, 0);
      }
    }
  };

  auto expand = [&](f32x4 (&Sa)[4], f32x4 (&Sb)[4], bf16x8 (&pfa)[2], bf16x8 (&pfb)[2]) {
    bf16x4 pa[4], pb[4];
#pragma unroll
    for (int kvb = 0; kvb < 4; ++kvb) {
#pragma unroll
      for (int r = 0; r < 4; ++r) {
        float ea = __builtin_amdgcn_exp2f(Sa[kvb][r]);
        float eb = __builtin_amdgcn_exp2f(Sb[kvb][r]);
        la += ea; lb += eb;
        pa[kvb][r] = (__bf16)ea;
        pb[kvb][r] = (__bf16)eb;
      }
    }
#pragma unroll
    for (int kc2 = 0; kc2 < 2; ++kc2) {
      uint2 alo = __builtin_bit_cast(uint2, pa[kc2 * 2]);
      uint2 ahi = __builtin_bit_cast(uint2, pa[kc2 * 2 + 1]);
      uint4 wa; wa.x = alo.x; wa.y = alo.y; wa.z = ahi.x; wa.w = ahi.y;
      pfa[kc2] = __builtin_bit_cast(bf16x8, wa);
      uint2 blo = __builtin_bit_cast(uint2, pb[kc2 * 2]);
      uint2 bhi = __builtin_bit_cast(uint2, pb[kc2 * 2 + 1]);
      uint4 wb; wb.x = blo.x; wb.y = blo.y; wb.z = bhi.x; wb.w = bhi.y;
      pfb[kc2] = __builtin_bit_cast(bf16x8, wb);
    }
  };

  auto pv = [&](int bufIdx, bf16x8 (&pfa)[2], bf16x8 (&pfb)[2]) {
    const u16_t* Vcur = lds + 16384 + bufIdx * 8192;
#pragma unroll
    for (int kc2 = 0; kc2 < 2; ++kc2) {
#pragma unroll
      for (int dcb = 0; dcb < 8; ++dcb) {
        int chunk = ((kc2 << 2) + l4) ^ (l15 & 7);
        bf16x8 vf = *(const bf16x8*)(Vcur + (dcb * 16 + l15) * 64 + chunk * 8);
        oa[dcb] = __builtin_amdgcn_mfma_f32_16x16x32_bf16(vf, pfa[kc2], oa[dcb], 0, 0, 0);
        ob[dcb] = __builtin_amdgcn_mfma_f32_16x16x32_bf16(vf, pfb[kc2], ob[dcb], 0, 0, 0);
      }
    }
  };

  auto step = [&](int t, f32x4 (&Ia)[4], f32x4 (&Ib)[4], f32x4 (&Oa)[4], f32x4 (&Ob)[4]) {
    bf16x8 pfa[2], pfb[2];
    expand(Ia, Ib, pfa, pfb);
    asm volatile("s_waitcnt vmcnt(0)" ::: "memory");
    __builtin_amdgcn_s_barrier();
    __builtin_amdgcn_sched_barrier(0);
#pragma unroll
    for (int z = 0; z < 4; ++z)
#pragma unroll
      for (int r = 0; r < 4; ++r) { Oa[z][r] = 0.f; Ob[z][r] = 0.f; }
    __builtin_amdgcn_s_setprio(1);
    pv(t & 1, pfa, pfb);
    qk((t + 1) & 1, Oa, Ob);
    __builtin_amdgcn_s_setprio(0);
    __builtin_amdgcn_sched_barrier(0);
    __builtin_amdgcn_s_barrier();
    __builtin_amdgcn_sched_barrier(0);
    if (t + 2 < SEQ / 64) stage((t + 2) * 64, t & 1);
  };

  f32x4 sA[4] = {}, sB[4] = {}, tA[4], tB[4];

  stage(0, 0);
  stage(64, 1);
  asm volatile("s_waitcnt vmcnt(8)" ::: "memory");
  __builtin_amdgcn_s_barrier();
  __builtin_amdgcn_sched_barrier(0);
  qk(0, sA, sB);

  for (int p = 0; p < 15; ++p) {
    step(2 * p, sA, sB, tA, tB);
    step(2 * p + 1, tA, tB, sA, sB);
  }
  step(30, sA, sB, tA, tB);
  {
    bf16x8 pfa[2], pfb[2];
    expand(tA, tB, pfa, pfb);
    pv(1, pfa, pfb);
  }

  la += __shfl_xor(la, 16); la += __shfl_xor(la, 32);
  lb += __shfl_xor(lb, 16); lb += __shfl_xor(lb, 32);
  float inva = 1.0f / la, invb = 1.0f / lb;

#pragma unroll
  for (int half = 0; half < 2; ++half) {
    u16_t* Owave = lds + half * 8704 + wid * 2176;
    const f32x4* oacc = half ? ob : oa;
    float inv = half ? invb : inva;
#pragma unroll
    for (int dcb = 0; dcb < 8; ++dcb) {
      bf16x4 ov;
#pragma unroll
      for (int r = 0; r < 4; ++r) ov[r] = (__bf16)(oacc[dcb][r] * inv);
      *(uint2*)(Owave + l15 * 136 + dcb * 16 + l4 * 4) = __builtin_bit_cast(uint2, ov);
    }
#pragma unroll
    for (int pass = 0; pass < 4; ++pass) {
      int rowq = pass * 4 + l4;
      int4 v = *(const int4*)(Owave + rowq * 136 + l15 * 8);
      int s = q0 + wid * 32 + half * 16 + rowq;
      *(int4*)(attn_out + ((size_t)(b * SEQ + s)) * DMODEL + h * HDIM + l15 * 8) = v;
    }
  }
}

// ---------------- launcher ----------------

extern "C" void kernel_launch(void* const* d_in, const int* in_sizes, int n_in,
                              void* d_out, int out_size, void* d_ws, size_t ws_size,
                              hipStream_t stream) {
  (void)in_sizes; (void)n_in; (void)out_size; (void)ws_size;
  const float* x  = (const float*)d_in[0];
  const float* rf = (const float*)d_in[1];
  const float* Wq = (const float*)d_in[2];
  const float* bq = (const float*)d_in[3];
  const float* Wk = (const float*)d_in[4];
  const float* bk = (const float*)d_in[5];
  const float* Wv = (const float*)d_in[6];
  const float* bv = (const float*)d_in[7];
  const float* Wo = (const float*)d_in[8];
  const float* bo = (const float*)d_in[9];
  float* out = (float*)d_out;

  char* ws = (char*)d_ws;
  u16_t* xb    = (u16_t*)ws;  ws += (size_t)MROWS * DMODEL * 2;
  u16_t* Wqkvt = (u16_t*)ws;  ws += (size_t)NQKV * DMODEL * 2;
  u16_t* Wot   = (u16_t*)ws;  ws += (size_t)DMODEL * DMODEL * 2;
  float* bqkv  = (float*)ws;  ws += (size_t)NQKV * 4;
  float* cosT  = (float*)ws;  ws += (size_t)SEQ * (HDIM / 2) * 4;
  float* sinT  = (float*)ws;  ws += (size_t)SEQ * (HDIM / 2) * 4;
  u16_t* Qb    = (u16_t*)ws;  ws += (size_t)NB * NHEAD * SEQ * HDIM * 2;
  u16_t* Kb    = (u16_t*)ws;  ws += (size_t)NB * NGRP * SEQ * HDIM * 2;
  u16_t* Vt    = (u16_t*)ws;  ws += (size_t)NB * NGRP * HDIM * SEQ * 2;
  u16_t* attn  = xb;  // alias: xb dead after GEMM1 (strict stream ordering)

  k_cast_x<<<MROWS * DMODEL / 1024, 256, 0, stream>>>(x, xb);
  k_tables<<<SEQ * (HDIM / 2) / 256, 256, 0, stream>>>(rf, cosT, sinT);
  k_bias<<<NQKV / 256, 256, 0, stream>>>(bq, bk, bv, bqkv);

  dim3 tgq(DMODEL / 64, DMODEL / 64);
  dim3 tgk(NKV / 64, DMODEL / 64);
  k_transpose_cast<<<tgq, 256, 0, stream>>>(Wq, DMODEL, Wqkvt, DMODEL);
  k_transpose_cast<<<tgk, 256, 0, stream>>>(Wk, NKV, Wqkvt + (size_t)DMODEL * DMODEL, DMODEL);
  k_transpose_cast<<<tgk, 256, 0, stream>>>(Wv, NKV, Wqkvt + (size_t)(DMODEL + NKV) * DMODEL, DMODEL);
  k_transpose_cast<<<tgq, 256, 0, stream>>>(Wo, DMODEL, Wot, DMODEL);

  // GEMM1: 4096 x 3072 x 2048, 512-thread blocks
  k_gemm<1><<<dim3(NQKV / 128, MROWS / 128), 512, 0, stream>>>(
      xb, Wqkvt, bqkv, nullptr, Qb, Kb, Vt, cosT, sinT, MROWS, NQKV, DMODEL);

  dim3 ga(SEQ / 128, NB * NHEAD);
  k_attn<<<ga, 256, 0, stream>>>(Qb, Kb, Vt, attn);

  // GEMM2: 4096 x 2048 x 2048, 512-thread blocks
  k_gemm<0><<<dim3(DMODEL / 128, MROWS / 128), 512, 0, stream>>>(
      attn, Wot, bo, out, nullptr, nullptr, nullptr, nullptr, nullptr, MROWS, DMODEL, DMODEL);
}

// Round 16
// 177.297 us; speedup vs baseline: 1.1653x; 1.0530x over previous
//
#include <hip/hip_runtime.h>
#include <cstdint>
#include <cstddef>

#define NB 2
#define SEQ 2048
#define DMODEL 2048
#define NHEAD 16
#define HDIM 128
#define NGRP 4
#define NKV (NGRP * HDIM)          // 512
#define NQKV (DMODEL + 2 * NKV)    // 3072
#define MROWS (NB * SEQ)           // 4096
// 1/sqrt(128) * log2(e): Q pre-scale so softmax uses exp2 directly
#define QSCALE_LOG2E 0.12751743f

typedef unsigned short u16_t;
typedef unsigned int u32_t;
typedef __bf16 bf16x8 __attribute__((ext_vector_type(8)));
typedef __bf16 bf16x4 __attribute__((ext_vector_type(4)));
typedef float f32x4 __attribute__((ext_vector_type(4)));

static __device__ __forceinline__ u16_t f2bf(float f) {
  u32_t u = __builtin_bit_cast(u32_t, f);
  u32_t r = u + 0x7FFFu + ((u >> 16) & 1u);
  return (u16_t)(r >> 16);
}

// ---------------- merged prep kernel ----------------
// sections by blockIdx: [0,8192) cast_x | [8192,8704) tables | [8704,8716) bias
// | [8716,9740) T(Wq) | [9740,9996) T(Wk) | [9996,10252) T(Wv) | [10252,11276) T(Wo)

__global__ __launch_bounds__(256) void k_prep(
    const float* __restrict__ x, const float* __restrict__ rf,
    const float* __restrict__ bq, const float* __restrict__ bk, const float* __restrict__ bv,
    const float* __restrict__ Wq, const float* __restrict__ Wk,
    const float* __restrict__ Wv, const float* __restrict__ Wo,
    u16_t* __restrict__ xb, float* __restrict__ cosT, float* __restrict__ sinT,
    float* __restrict__ bqkv, u16_t* __restrict__ Wqkvt, u16_t* __restrict__ Wot) {
  __shared__ float tile[64][65];
  int bid = blockIdx.x, t = threadIdx.x;

  if (bid < 8192) {                                   // cast x -> bf16 (float4/thread)
    int i = bid * 256 + t;
    float4 v = ((const float4*)x)[i];
    uint2 pk;
    pk.x = (u32_t)f2bf(v.x) | ((u32_t)f2bf(v.y) << 16);
    pk.y = (u32_t)f2bf(v.z) | ((u32_t)f2bf(v.w) << 16);
    ((uint2*)xb)[i] = pk;
    return;
  }
  bid -= 8192;
  if (bid < 512) {                                    // cos/sin tables
    int i = bid * 256 + t;
    float f = rf[i];
    cosT[i] = cosf(f);
    sinT[i] = sinf(f);
    return;
  }
  bid -= 512;
  if (bid < 12) {                                     // concat bias
    int i = bid * 256 + t;
    float v = (i < DMODEL) ? bq[i] : (i < DMODEL + NKV ? bk[i - DMODEL] : bv[i - DMODEL - NKV]);
    bqkv[i] = v;
    return;
  }
  bid -= 12;

  const float* W; u16_t* Wt; int N, n0, k0;
  if (bid < 1024) {
    W = Wq; Wt = Wqkvt; N = DMODEL;
    n0 = (bid & 31) * 64; k0 = (bid >> 5) * 64;
  } else if (bid < 1280) {
    int b2 = bid - 1024;
    W = Wk; Wt = Wqkvt + (size_t)DMODEL * DMODEL; N = NKV;
    n0 = (b2 & 7) * 64; k0 = (b2 >> 3) * 64;
  } else if (bid < 1536) {
    int b2 = bid - 1280;
    W = Wv; Wt = Wqkvt + (size_t)(DMODEL + NKV) * DMODEL; N = NKV;
    n0 = (b2 & 7) * 64; k0 = (b2 >> 3) * 64;
  } else {
    int b2 = bid - 1536;
    W = Wo; Wt = Wot; N = DMODEL;
    n0 = (b2 & 31) * 64; k0 = (b2 >> 5) * 64;
  }
  const int K = DMODEL;
#pragma unroll
  for (int pass = 0; pass < 4; ++pass) {
    int slot = pass * 256 + t;
    int r = slot >> 4, c4 = (slot & 15) * 4;
    float4 v = *(const float4*)(W + (size_t)(k0 + r) * N + n0 + c4);
    tile[r][c4] = v.x; tile[r][c4 + 1] = v.y; tile[r][c4 + 2] = v.z; tile[r][c4 + 3] = v.w;
  }
  __syncthreads();
  int nr = t >> 2, seg = t & 3;
  alignas(16) u16_t o[16];
#pragma unroll
  for (int kk = 0; kk < 16; ++kk) o[kk] = f2bf(tile[seg * 16 + kk][nr]);
  u16_t* dst = Wt + (size_t)(n0 + nr) * K + k0 + seg * 16;
  ((int4*)dst)[0] = ((const int4*)o)[0];
  ((int4*)dst)[1] = ((const int4*)o)[1];
}

// ---------------- GEMM (unchanged from round 15) ----------------
// 128x128 tile, BK=64, 512 threads / 8 waves (wave 64x32, acc[4][2]).
// Two-barrier counted ledger; 64KB 2-slot LDS; source-preswizzled cs=c^(row&7).

template <int EPI>
__global__ __launch_bounds__(512, 4) void k_gemm(
    const u16_t* __restrict__ A, const u16_t* __restrict__ Bt, const float* __restrict__ bias,
    float* __restrict__ Cout, u16_t* __restrict__ Qb, u16_t* __restrict__ Kb,
    u16_t* __restrict__ Vt, const float* __restrict__ cosT, const float* __restrict__ sinT,
    int M, int N, int K) {
  __shared__ u16_t lds[32768];
  int tid = threadIdx.x;
  int wid = tid >> 6, lane = tid & 63;
  int l15 = lane & 15, l4 = lane >> 4;
  int wrow = wid >> 2, wcol = wid & 3;

  int m0 = blockIdx.y << 7, n0 = blockIdx.x << 7;

  f32x4 acc[4][2] = {};

  auto stage = [&](int t) {
    u16_t* Al = lds + (t & 1) * 8192;
    u16_t* Bl = lds + 16384 + (t & 1) * 8192;
    int kbase = t * 64;
#pragma unroll
    for (int ss = 0; ss < 2; ++ss) {
      int slot = tid + ss * 512;
      int row = slot >> 3, c = slot & 7;
      int cs = c ^ (row & 7);
      __builtin_amdgcn_global_load_lds(
          (const __attribute__((address_space(1))) u32_t*)(A + (size_t)(m0 + row) * K + kbase + cs * 8),
          (__attribute__((address_space(3))) u32_t*)(Al + slot * 8), 16, 0, 0);
      __builtin_amdgcn_global_load_lds(
          (const __attribute__((address_space(1))) u32_t*)(Bt + (size_t)(n0 + row) * K + kbase + cs * 8),
          (__attribute__((address_space(3))) u32_t*)(Bl + slot * 8), 16, 0, 0);
    }
  };

  stage(0);
  stage(1);

  const int NT = K >> 6;
  for (int t = 0; t < NT; ++t) {
    if (t == NT - 1) {
      asm volatile("s_waitcnt vmcnt(0)" ::: "memory");
    } else {
      asm volatile("s_waitcnt vmcnt(4)" ::: "memory");
    }
    __builtin_amdgcn_s_barrier();
    __builtin_amdgcn_sched_barrier(0);

    const u16_t* Acur = lds + (t & 1) * 8192;
    const u16_t* Bcur = lds + 16384 + (t & 1) * 8192;

#pragma unroll
    for (int kk = 0; kk < 2; ++kk) {
      int chunk = ((kk << 2) + l4) ^ (l15 & 7);
      bf16x8 af[4], bfr[2];
#pragma unroll
      for (int i = 0; i < 4; ++i)
        af[i] = *(const bf16x8*)(Acur + (wrow * 64 + i * 16 + l15) * 64 + chunk * 8);
#pragma unroll
      for (int j = 0; j < 2; ++j)
        bfr[j] = *(const bf16x8*)(Bcur + (wcol * 32 + j * 16 + l15) * 64 + chunk * 8);

      __builtin_amdgcn_s_setprio(1);
#pragma unroll
      for (int i = 0; i < 4; ++i)
#pragma unroll
        for (int j = 0; j < 2; ++j)
          acc[i][j] = __builtin_amdgcn_mfma_f32_16x16x32_bf16(af[i], bfr[j], acc[i][j], 0, 0, 0);
      __builtin_amdgcn_s_setprio(0);
    }

    __builtin_amdgcn_sched_barrier(0);
    __builtin_amdgcn_s_barrier();
    __builtin_amdgcn_sched_barrier(0);
    if (t + 2 < NT) stage(t + 2);
  }

  if (EPI == 0) {
#pragma unroll
    for (int j = 0; j < 2; ++j) {
      int n = n0 + wcol * 32 + j * 16 + l15;
      float bs = bias[n];
#pragma unroll
      for (int i = 0; i < 4; ++i) {
        int mbase = m0 + wrow * 64 + i * 16 + l4 * 4;
#pragma unroll
        for (int r = 0; r < 4; ++r)
          Cout[(size_t)(mbase + r) * N + n] = acc[i][j][r] + bs;
      }
    }
  } else {
    bool isV = (n0 >= DMODEL + NKV);
    bool isK = (n0 >= DMODEL) && !isV;
#pragma unroll
    for (int j = 0; j < 2; ++j) {
      int n = n0 + wcol * 32 + j * 16 + l15;
      float bs = bias[n];
      int d = n & (HDIM - 1);
      int p = d >> 1;
      bool evn = !(d & 1);
#pragma unroll
      for (int i = 0; i < 4; ++i) {
        int mbase = m0 + wrow * 64 + i * 16 + l4 * 4;
        if (isV) {
          int g = (n - DMODEL - NKV) >> 7;
          int b = mbase >> 11, s0 = mbase & (SEQ - 1);
          u16_t o[4];
#pragma unroll
          for (int r = 0; r < 4; ++r) o[r] = f2bf(acc[i][j][r] + bs);
          uint2 pk;
          pk.x = (u32_t)o[0] | ((u32_t)o[1] << 16);
          pk.y = (u32_t)o[2] | ((u32_t)o[3] << 16);
          *(uint2*)(Vt + ((size_t)(b * NGRP + g) * HDIM + d) * SEQ + s0) = pk;
        } else {
#pragma unroll
          for (int r = 0; r < 4; ++r) {
            int m = mbase + r;
            int b = m >> 11, s = m & (SEQ - 1);
            float val = acc[i][j][r] + bs;
            float pv = __shfl_xor(val, 1);
            float c = cosT[s * (HDIM / 2) + p];
            float sn = sinT[s * (HDIM / 2) + p];
            float outv = evn ? (val * c - pv * sn) : (pv * sn + val * c);
            if (isK) {
              int g = (n - DMODEL) >> 7;
              Kb[((size_t)(b * NGRP + g) * SEQ + s) * HDIM + d] = f2bf(outv);
            } else {
              int h = n >> 7;
              Qb[((size_t)(b * NHEAD + h) * SEQ + s) * HDIM + d] = f2bf(outv * QSCALE_LOG2E);
            }
          }
        }
      }
    }
  }
}

// ---------------- flash attention (round 16: counted-vmcnt K3/V2 ledger) --------
// LDS: K slots 0..2 at ks*8192, V slots 0..1 at 24576+vs*8192 (u16), 80KB.
// Steady state, step t: expand(t) -> vmcnt(8) [retires end-of-(t-1) batch
// {K(t+1),V(t)}; leaves end-of-t... i.e. {K(t+2),V(t+1)} in flight]
// -> bar#1 -> pv(t,vslot t%2) || qk(t+1,kslot (t+1)%3) -> bar#2
// -> stageK(t+3 -> slot t%3), stageV(t+2 -> slot t%2).
// Tail: step 30 waits vmcnt(4) (end-of-29 batch is only V31); final pv(31)
// behind vmcnt(0)+barrier. Slot audit in comments above each overwrite.

__global__ __launch_bounds__(256, 2) void k_attn(
    const u16_t* __restrict__ Qb, const u16_t* __restrict__ Kb, const u16_t* __restrict__ Vt,
    u16_t* __restrict__ attn_out) {
  __shared__ u16_t lds[40960];   // 3 K slots + 2 V slots

  int tid = threadIdx.x, wid = tid >> 6, lane = tid & 63;
  int l15 = lane & 15, l4 = lane >> 4;
  int bh = blockIdx.y;
  int b = bh >> 4, h = bh & 15, g = h >> 2;
  int q0 = blockIdx.x * 128;
  const u16_t* Qhead = Qb + (size_t)(b * NHEAD + h) * SEQ * HDIM;
  const u16_t* Khead = Kb + (size_t)(b * NGRP + g) * SEQ * HDIM;
  const u16_t* Vhead = Vt + (size_t)(b * NGRP + g) * HDIM * SEQ;

  bf16x8 qfa[4], qfb[4];
#pragma unroll
  for (int kc = 0; kc < 4; ++kc) {
    qfa[kc] = *(const bf16x8*)(Qhead + (size_t)(q0 + wid * 32 + l15) * HDIM + kc * 32 + l4 * 8);
    qfb[kc] = *(const bf16x8*)(Qhead + (size_t)(q0 + wid * 32 + 16 + l15) * HDIM + kc * 32 + l4 * 8);
  }

  f32x4 oa[8] = {}, ob[8] = {};
  f32x4 lav = {0.f, 0.f, 0.f, 0.f}, lbv = {0.f, 0.f, 0.f, 0.f};  // 4-way partial sums

  auto stageK = [&](int kv0, int ks) {
    u16_t* Kl = lds + ks * 8192;
#pragma unroll
    for (int ss = 0; ss < 4; ++ss) {
      int slot = tid + ss * 256;
      int rK = slot >> 4;
      int cK = (slot & 15) ^ ((rK & 3) | (((rK >> 3) & 1) << 2));
      __builtin_amdgcn_global_load_lds(
          (const __attribute__((address_space(1))) u32_t*)(Khead + (size_t)(kv0 + rK) * HDIM + cK * 8),
          (__attribute__((address_space(3))) u32_t*)(Kl + slot * 8), 16, 0, 0);
    }
  };
  auto stageV = [&](int kv0, int vs) {
    u16_t* Vl = lds + 24576 + vs * 8192;
#pragma unroll
    for (int ss = 0; ss < 4; ++ss) {
      int slot = tid + ss * 256;
      int rV = slot >> 3, cV = (slot & 7) ^ (rV & 7);
      __builtin_amdgcn_global_load_lds(
          (const __attribute__((address_space(1))) u32_t*)(Vhead + (size_t)rV * SEQ + kv0 + cV * 8),
          (__attribute__((address_space(3))) u32_t*)(Vl + slot * 8), 16, 0, 0);
    }
  };

  auto qk = [&](int ks, f32x4 (&Sa)[4], f32x4 (&Sb)[4]) {
    const u16_t* Kcur = lds + ks * 8192;
#pragma unroll
    for (int kc = 0; kc < 4; ++kc) {
#pragma unroll
      for (int kvb = 0; kvb < 4; ++kvb) {
        int row = (l15 >> 2) * 8 + ((kvb & 1) << 2) + (l15 & 3) + ((kvb >> 1) << 5);
        int chunk = ((kc << 2) + l4) ^ (l15 & 7);
        bf16x8 kf = *(const bf16x8*)(Kcur + row * 128 + chunk * 8);
        Sa[kvb] = __builtin_amdgcn_mfma_f32_16x16x32_bf16(kf, qfa[kc], Sa[kvb], 0, 0, 0);
        Sb[kvb] = __builtin_amdgcn_mfma_f32_16x16x32_bf16(kf, qfb[kc], Sb[kvb], 0, 0, 0);
      }
    }
  };

  auto expand = [&](f32x4 (&Sa)[4], f32x4 (&Sb)[4], bf16x8 (&pfa)[2], bf16x8 (&pfb)[2]) {
    bf16x4 pa[4], pb[4];
#pragma unroll
    for (int kvb = 0; kvb < 4; ++kvb) {
#pragma unroll
      for (int r = 0; r < 4; ++r) {
        float ea = __builtin_amdgcn_exp2f(Sa[kvb][r]);
        float eb = __builtin_amdgcn_exp2f(Sb[kvb][r]);
        lav[r] += ea; lbv[r] += eb;    // 4 independent chains per acc
        pa[kvb][r] = (__bf16)ea;
        pb[kvb][r] = (__bf16)eb;
      }
    }
#pragma unroll
    for (int kc2 = 0; kc2 < 2; ++kc2) {
      uint2 alo = __builtin_bit_cast(uint2, pa[kc2 * 2]);
      uint2 ahi = __builtin_bit_cast(uint2, pa[kc2 * 2 + 1]);
      uint4 wa; wa.x = alo.x; wa.y = alo.y; wa.z = ahi.x; wa.w = ahi.y;
      pfa[kc2] = __builtin_bit_cast(bf16x8, wa);
      uint2 blo = __builtin_bit_cast(uint2, pb[kc2 * 2]);
      uint2 bhi = __builtin_bit_cast(uint2, pb[kc2 * 2 + 1]);
      uint4 wb; wb.x = blo.x; wb.y = blo.y; wb.z = bhi.x; wb.w = bhi.y;
      pfb[kc2] = __builtin_bit_cast(bf16x8, wb);
    }
  };

  auto pv = [&](int vs, bf16x8 (&pfa)[2], bf16x8 (&pfb)[2]) {
    const u16_t* Vcur = lds + 24576 + vs * 8192;
#pragma unroll
    for (int kc2 = 0; kc2 < 2; ++kc2) {
#pragma unroll
      for (int dcb = 0; dcb < 8; ++dcb) {
        int chunk = ((kc2 << 2) + l4) ^ (l15 & 7);
        bf16x8 vf = *(const bf16x8*)(Vcur + (dcb * 16 + l15) * 64 + chunk * 8);
        oa[dcb] = __builtin_amdgcn_mfma_f32_16x16x32_bf16(vf, pfa[kc2], oa[dcb], 0, 0, 0);
        ob[dcb] = __builtin_amdgcn_mfma_f32_16x16x32_bf16(vf, pfb[kc2], ob[dcb], 0, 0, 0);
      }
    }
  };

  const int NT = SEQ / 64;   // 32

  // step t: see header. `last` = (t == NT-2): end-of-(t-1) batch was only V(NT-1).
  auto step = [&](int t, bool last, f32x4 (&Ia)[4], f32x4 (&Ib)[4],
                  f32x4 (&Oa)[4], f32x4 (&Ob)[4]) {
    bf16x8 pfa[2], pfb[2];
    expand(Ia, Ib, pfa, pfb);
    if (last) {
      asm volatile("s_waitcnt vmcnt(4)" ::: "memory");
    } else {
      asm volatile("s_waitcnt vmcnt(8)" ::: "memory");
    }
    __builtin_amdgcn_s_barrier();                    // K(t+1), V(t) valid block-wide
    __builtin_amdgcn_sched_barrier(0);
#pragma unroll
    for (int z = 0; z < 4; ++z)
#pragma unroll
      for (int r = 0; r < 4; ++r) { Oa[z][r] = 0.f; Ob[z][r] = 0.f; }
    __builtin_amdgcn_s_setprio(1);
    pv(t & 1, pfa, pfb);                             // V(t) in vslot t%2
    qk((t + 1) % 3, Oa, Ob);                         // K(t+1) in kslot (t+1)%3
    __builtin_amdgcn_s_setprio(0);
    __builtin_amdgcn_sched_barrier(0);
    __builtin_amdgcn_s_barrier();                    // all reads of this step done
    __builtin_amdgcn_sched_barrier(0);
    // overwrites: kslot t%3 held K(t), last read step t-1; vslot t%2 held V(t),
    // read above -- both behind the barrier just crossed.
    if (t + 3 < NT) stageK((t + 3) * 64, t % 3);
    if (t + 2 < NT) stageV((t + 2) * 64, t & 1);
  };

  f32x4 sA[4] = {}, sB[4] = {}, tA[4], tB[4];

  // prologue: K0,K1,V0 issued; vmcnt(8) retires K0; then K2,V1 issued.
  stageK(0, 0);
  stageK(64, 1);
  stageV(0, 0);
  asm volatile("s_waitcnt vmcnt(8)" ::: "memory");
  __builtin_amdgcn_s_barrier();
  __builtin_amdgcn_sched_barrier(0);
  stageK(128, 2);
  stageV(64, 1);
  qk(0, sA, sB);

  for (int p = 0; p < 15; ++p) {
    step(2 * p, false, sA, sB, tA, tB);
    step(2 * p + 1, false, tA, tB, sA, sB);
  }
  step(30, true, sA, sB, tA, tB);
  {
    bf16x8 pfa[2], pfb[2];
    expand(tA, tB, pfa, pfb);                        // tile 31 scores
    asm volatile("s_waitcnt vmcnt(0)" ::: "memory"); // V(31) landed (all waves...)
    __builtin_amdgcn_s_barrier();                    // ...confirmed block-wide
    __builtin_amdgcn_sched_barrier(0);
    pv(1, pfa, pfb);                                 // V(31) in vslot 1
  }

  float la = lav[0] + lav[1] + lav[2] + lav[3];
  float lb = lbv[0] + lbv[1] + lbv[2] + lbv[3];
  la += __shfl_xor(la, 16); la += __shfl_xor(la, 32);
  lb += __shfl_xor(lb, 16); lb += __shfl_xor(lb, 32);
  float inva = 1.0f / la, invb = 1.0f / lb;

#pragma unroll
  for (int half = 0; half < 2; ++half) {
    u16_t* Owave = lds + half * 8704 + wid * 2176;
    const f32x4* oacc = half ? ob : oa;
    float inv = half ? invb : inva;
#pragma unroll
    for (int dcb = 0; dcb < 8; ++dcb) {
      bf16x4 ov;
#pragma unroll
      for (int r = 0; r < 4; ++r) ov[r] = (__bf16)(oacc[dcb][r] * inv);
      *(uint2*)(Owave + l15 * 136 + dcb * 16 + l4 * 4) = __builtin_bit_cast(uint2, ov);
    }
#pragma unroll
    for (int pass = 0; pass < 4; ++pass) {
      int rowq = pass * 4 + l4;
      int4 v = *(const int4*)(Owave + rowq * 136 + l15 * 8);
      int s = q0 + wid * 32 + half * 16 + rowq;
      *(int4*)(attn_out + ((size_t)(b * SEQ + s)) * DMODEL + h * HDIM + l15 * 8) = v;
    }
  }
}

// ---------------- launcher ----------------

extern "C" void kernel_launch(void* const* d_in, const int* in_sizes, int n_in,
                              void* d_out, int out_size, void* d_ws, size_t ws_size,
                              hipStream_t stream) {
  (void)in_sizes; (void)n_in; (void)out_size; (void)ws_size;
  const float* x  = (const float*)d_in[0];
  const float* rf = (const float*)d_in[1];
  const float* Wq = (const float*)d_in[2];
  const float* bq = (const float*)d_in[3];
  const float* Wk = (const float*)d_in[4];
  const float* bk = (const float*)d_in[5];
  const float* Wv = (const float*)d_in[6];
  const float* bv = (const float*)d_in[7];
  const float* Wo = (const float*)d_in[8];
  const float* bo = (const float*)d_in[9];
  float* out = (float*)d_out;

  char* ws = (char*)d_ws;
  u16_t* xb    = (u16_t*)ws;  ws += (size_t)MROWS * DMODEL * 2;
  u16_t* Wqkvt = (u16_t*)ws;  ws += (size_t)NQKV * DMODEL * 2;
  u16_t* Wot   = (u16_t*)ws;  ws += (size_t)DMODEL * DMODEL * 2;
  float* bqkv  = (float*)ws;  ws += (size_t)NQKV * 4;
  float* cosT  = (float*)ws;  ws += (size_t)SEQ * (HDIM / 2) * 4;
  float* sinT  = (float*)ws;  ws += (size_t)SEQ * (HDIM / 2) * 4;
  u16_t* Qb    = (u16_t*)ws;  ws += (size_t)NB * NHEAD * SEQ * HDIM * 2;
  u16_t* Kb    = (u16_t*)ws;  ws += (size_t)NB * NGRP * SEQ * HDIM * 2;
  u16_t* Vt    = (u16_t*)ws;  ws += (size_t)NB * NGRP * HDIM * SEQ * 2;
  u16_t* attn  = xb;  // alias: xb dead after GEMM1 (strict stream ordering)

  // merged prep: 8192 + 512 + 12 + 1024 + 256 + 256 + 1024 = 11276 blocks
  k_prep<<<11276, 256, 0, stream>>>(x, rf, bq, bk, bv, Wq, Wk, Wv, Wo,
                                    xb, cosT, sinT, bqkv, Wqkvt, Wot);

  // GEMM1: 4096 x 3072 x 2048, 512-thread blocks
  k_gemm<1><<<dim3(NQKV / 128, MROWS / 128), 512, 0, stream>>>(
      xb, Wqkvt, bqkv, nullptr, Qb, Kb, Vt, cosT, sinT, MROWS, NQKV, DMODEL);

  dim3 ga(SEQ / 128, NB * NHEAD);
  k_attn<<<ga, 256, 0, stream>>>(Qb, Kb, Vt, attn);

  // GEMM2: 4096 x 2048 x 2048, 512-thread blocks
  k_gemm<0><<<dim3(DMODEL / 128, MROWS / 128), 512, 0, stream>>>(
      attn, Wot, bo, out, nullptr, nullptr, nullptr, nullptr, nullptr, MROWS, DMODEL, DMODEL);
}

// Round 17
// 174.366 us; speedup vs baseline: 1.1848x; 1.0168x over previous
//
#include <hip/hip_runtime.h>
#include <cstdint>
#include <cstddef>

#define NB 2
#define SEQ 2048
#define DMODEL 2048
#define NHEAD 16
#define HDIM 128
#define NGRP 4
#define NKV (NGRP * HDIM)          // 512
#define NQKV (DMODEL + 2 * NKV)    // 3072
#define MROWS (NB * SEQ)           // 4096
// 1/sqrt(128) * log2(e): Q pre-scale so softmax uses exp2 directly
#define QSCALE_LOG2E 0.12751743f

typedef unsigned short u16_t;
typedef unsigned int u32_t;
typedef __bf16 bf16x8 __attribute__((ext_vector_type(8)));
typedef __bf16 bf16x4 __attribute__((ext_vector_type(4)));
typedef float f32x4 __attribute__((ext_vector_type(4)));

static __device__ __forceinline__ u16_t f2bf(float f) {
  u32_t u = __builtin_bit_cast(u32_t, f);
  u32_t r = u + 0x7FFFu + ((u >> 16) & 1u);
  return (u16_t)(r >> 16);
}

// ---------------- merged prep kernel (unchanged from round 16) ----------------
// sections by blockIdx: [0,8192) cast_x | [8192,8704) tables | [8704,8716) bias
// | [8716,9740) T(Wq) | [9740,9996) T(Wk) | [9996,10252) T(Wv) | [10252,11276) T(Wo)

__global__ __launch_bounds__(256) void k_prep(
    const float* __restrict__ x, const float* __restrict__ rf,
    const float* __restrict__ bq, const float* __restrict__ bk, const float* __restrict__ bv,
    const float* __restrict__ Wq, const float* __restrict__ Wk,
    const float* __restrict__ Wv, const float* __restrict__ Wo,
    u16_t* __restrict__ xb, float* __restrict__ cosT, float* __restrict__ sinT,
    float* __restrict__ bqkv, u16_t* __restrict__ Wqkvt, u16_t* __restrict__ Wot) {
  __shared__ float tile[64][65];
  int bid = blockIdx.x, t = threadIdx.x;

  if (bid < 8192) {                                   // cast x -> bf16 (float4/thread)
    int i = bid * 256 + t;
    float4 v = ((const float4*)x)[i];
    uint2 pk;
    pk.x = (u32_t)f2bf(v.x) | ((u32_t)f2bf(v.y) << 16);
    pk.y = (u32_t)f2bf(v.z) | ((u32_t)f2bf(v.w) << 16);
    ((uint2*)xb)[i] = pk;
    return;
  }
  bid -= 8192;
  if (bid < 512) {                                    // cos/sin tables
    int i = bid * 256 + t;
    float f = rf[i];
    cosT[i] = cosf(f);
    sinT[i] = sinf(f);
    return;
  }
  bid -= 512;
  if (bid < 12) {                                     // concat bias
    int i = bid * 256 + t;
    float v = (i < DMODEL) ? bq[i] : (i < DMODEL + NKV ? bk[i - DMODEL] : bv[i - DMODEL - NKV]);
    bqkv[i] = v;
    return;
  }
  bid -= 12;

  const float* W; u16_t* Wt; int N, n0, k0;
  if (bid < 1024) {
    W = Wq; Wt = Wqkvt; N = DMODEL;
    n0 = (bid & 31) * 64; k0 = (bid >> 5) * 64;
  } else if (bid < 1280) {
    int b2 = bid - 1024;
    W = Wk; Wt = Wqkvt + (size_t)DMODEL * DMODEL; N = NKV;
    n0 = (b2 & 7) * 64; k0 = (b2 >> 3) * 64;
  } else if (bid < 1536) {
    int b2 = bid - 1280;
    W = Wv; Wt = Wqkvt + (size_t)(DMODEL + NKV) * DMODEL; N = NKV;
    n0 = (b2 & 7) * 64; k0 = (b2 >> 3) * 64;
  } else {
    int b2 = bid - 1536;
    W = Wo; Wt = Wot; N = DMODEL;
    n0 = (b2 & 31) * 64; k0 = (b2 >> 5) * 64;
  }
  const int K = DMODEL;
#pragma unroll
  for (int pass = 0; pass < 4; ++pass) {
    int slot = pass * 256 + t;
    int r = slot >> 4, c4 = (slot & 15) * 4;
    float4 v = *(const float4*)(W + (size_t)(k0 + r) * N + n0 + c4);
    tile[r][c4] = v.x; tile[r][c4 + 1] = v.y; tile[r][c4 + 2] = v.z; tile[r][c4 + 3] = v.w;
  }
  __syncthreads();
  int nr = t >> 2, seg = t & 3;
  alignas(16) u16_t o[16];
#pragma unroll
  for (int kk = 0; kk < 16; ++kk) o[kk] = f2bf(tile[seg * 16 + kk][nr]);
  u16_t* dst = Wt + (size_t)(n0 + nr) * K + k0 + seg * 16;
  ((int4*)dst)[0] = ((const int4*)o)[0];
  ((int4*)dst)[1] = ((const int4*)o)[1];
}

// ---------------- GEMM (unchanged from round 15/16) ----------------
// 128x128 tile, BK=64, 512 threads / 8 waves (wave 64x32, acc[4][2]).
// Two-barrier counted ledger; 64KB 2-slot LDS; source-preswizzled cs=c^(row&7).

template <int EPI>
__global__ __launch_bounds__(512, 4) void k_gemm(
    const u16_t* __restrict__ A, const u16_t* __restrict__ Bt, const float* __restrict__ bias,
    float* __restrict__ Cout, u16_t* __restrict__ Qb, u16_t* __restrict__ Kb,
    u16_t* __restrict__ Vt, const float* __restrict__ cosT, const float* __restrict__ sinT,
    int M, int N, int K) {
  __shared__ u16_t lds[32768];
  int tid = threadIdx.x;
  int wid = tid >> 6, lane = tid & 63;
  int l15 = lane & 15, l4 = lane >> 4;
  int wrow = wid >> 2, wcol = wid & 3;

  int m0 = blockIdx.y << 7, n0 = blockIdx.x << 7;

  f32x4 acc[4][2] = {};

  auto stage = [&](int t) {
    u16_t* Al = lds + (t & 1) * 8192;
    u16_t* Bl = lds + 16384 + (t & 1) * 8192;
    int kbase = t * 64;
#pragma unroll
    for (int ss = 0; ss < 2; ++ss) {
      int slot = tid + ss * 512;
      int row = slot >> 3, c = slot & 7;
      int cs = c ^ (row & 7);
      __builtin_amdgcn_global_load_lds(
          (const __attribute__((address_space(1))) u32_t*)(A + (size_t)(m0 + row) * K + kbase + cs * 8),
          (__attribute__((address_space(3))) u32_t*)(Al + slot * 8), 16, 0, 0);
      __builtin_amdgcn_global_load_lds(
          (const __attribute__((address_space(1))) u32_t*)(Bt + (size_t)(n0 + row) * K + kbase + cs * 8),
          (__attribute__((address_space(3))) u32_t*)(Bl + slot * 8), 16, 0, 0);
    }
  };

  stage(0);
  stage(1);

  const int NT = K >> 6;
  for (int t = 0; t < NT; ++t) {
    if (t == NT - 1) {
      asm volatile("s_waitcnt vmcnt(0)" ::: "memory");
    } else {
      asm volatile("s_waitcnt vmcnt(4)" ::: "memory");
    }
    __builtin_amdgcn_s_barrier();
    __builtin_amdgcn_sched_barrier(0);

    const u16_t* Acur = lds + (t & 1) * 8192;
    const u16_t* Bcur = lds + 16384 + (t & 1) * 8192;

#pragma unroll
    for (int kk = 0; kk < 2; ++kk) {
      int chunk = ((kk << 2) + l4) ^ (l15 & 7);
      bf16x8 af[4], bfr[2];
#pragma unroll
      for (int i = 0; i < 4; ++i)
        af[i] = *(const bf16x8*)(Acur + (wrow * 64 + i * 16 + l15) * 64 + chunk * 8);
#pragma unroll
      for (int j = 0; j < 2; ++j)
        bfr[j] = *(const bf16x8*)(Bcur + (wcol * 32 + j * 16 + l15) * 64 + chunk * 8);

      __builtin_amdgcn_s_setprio(1);
#pragma unroll
      for (int i = 0; i < 4; ++i)
#pragma unroll
        for (int j = 0; j < 2; ++j)
          acc[i][j] = __builtin_amdgcn_mfma_f32_16x16x32_bf16(af[i], bfr[j], acc[i][j], 0, 0, 0);
      __builtin_amdgcn_s_setprio(0);
    }

    __builtin_amdgcn_sched_barrier(0);
    __builtin_amdgcn_s_barrier();
    __builtin_amdgcn_sched_barrier(0);
    if (t + 2 < NT) stage(t + 2);
  }

  if (EPI == 0) {
#pragma unroll
    for (int j = 0; j < 2; ++j) {
      int n = n0 + wcol * 32 + j * 16 + l15;
      float bs = bias[n];
#pragma unroll
      for (int i = 0; i < 4; ++i) {
        int mbase = m0 + wrow * 64 + i * 16 + l4 * 4;
#pragma unroll
        for (int r = 0; r < 4; ++r)
          Cout[(size_t)(mbase + r) * N + n] = acc[i][j][r] + bs;
      }
    }
  } else {
    bool isV = (n0 >= DMODEL + NKV);
    bool isK = (n0 >= DMODEL) && !isV;
#pragma unroll
    for (int j = 0; j < 2; ++j) {
      int n = n0 + wcol * 32 + j * 16 + l15;
      float bs = bias[n];
      int d = n & (HDIM - 1);
      int p = d >> 1;
      bool evn = !(d & 1);
#pragma unroll
      for (int i = 0; i < 4; ++i) {
        int mbase = m0 + wrow * 64 + i * 16 + l4 * 4;
        if (isV) {
          int g = (n - DMODEL - NKV) >> 7;
          int b = mbase >> 11, s0 = mbase & (SEQ - 1);
          u16_t o[4];
#pragma unroll
          for (int r = 0; r < 4; ++r) o[r] = f2bf(acc[i][j][r] + bs);
          uint2 pk;
          pk.x = (u32_t)o[0] | ((u32_t)o[1] << 16);
          pk.y = (u32_t)o[2] | ((u32_t)o[3] << 16);
          *(uint2*)(Vt + ((size_t)(b * NGRP + g) * HDIM + d) * SEQ + s0) = pk;
        } else {
#pragma unroll
          for (int r = 0; r < 4; ++r) {
            int m = mbase + r;
            int b = m >> 11, s = m & (SEQ - 1);
            float val = acc[i][j][r] + bs;
            float pv = __shfl_xor(val, 1);
            float c = cosT[s * (HDIM / 2) + p];
            float sn = sinT[s * (HDIM / 2) + p];
            float outv = evn ? (val * c - pv * sn) : (pv * sn + val * c);
            if (isK) {
              int g = (n - DMODEL) >> 7;
              Kb[((size_t)(b * NGRP + g) * SEQ + s) * HDIM + d] = f2bf(outv);
            } else {
              int h = n >> 7;
              Qb[((size_t)(b * NHEAD + h) * SEQ + s) * HDIM + d] = f2bf(outv * QSCALE_LOG2E);
            }
          }
        }
      }
    }
  }
}

// ---------------- flash attention (exact revert to round-15 version) ----------------
// 2-buffer K/V, R11-family ledger (measured 77.4-78.4 us stable, rounds 11-15).
// Per step t: expand(t) -> vmcnt(0) -> bar#1 -> pv(t) || qk(t+1) -> bar#2
//             -> stage(t+2) into slot t&1.

__global__ __launch_bounds__(256, 2) void k_attn(
    const u16_t* __restrict__ Qb, const u16_t* __restrict__ Kb, const u16_t* __restrict__ Vt,
    u16_t* __restrict__ attn_out) {
  __shared__ u16_t lds[32768];   // K0,K1,V0,V1: 8192 u16 each

  int tid = threadIdx.x, wid = tid >> 6, lane = tid & 63;
  int l15 = lane & 15, l4 = lane >> 4;
  int bh = blockIdx.y;
  int b = bh >> 4, h = bh & 15, g = h >> 2;
  int q0 = blockIdx.x * 128;
  const u16_t* Qhead = Qb + (size_t)(b * NHEAD + h) * SEQ * HDIM;
  const u16_t* Khead = Kb + (size_t)(b * NGRP + g) * SEQ * HDIM;
  const u16_t* Vhead = Vt + (size_t)(b * NGRP + g) * HDIM * SEQ;

  bf16x8 qfa[4], qfb[4];
#pragma unroll
  for (int kc = 0; kc < 4; ++kc) {
    qfa[kc] = *(const bf16x8*)(Qhead + (size_t)(q0 + wid * 32 + l15) * HDIM + kc * 32 + l4 * 8);
    qfb[kc] = *(const bf16x8*)(Qhead + (size_t)(q0 + wid * 32 + 16 + l15) * HDIM + kc * 32 + l4 * 8);
  }

  f32x4 oa[8] = {}, ob[8] = {};
  float la = 0.f, lb = 0.f;

  auto stage = [&](int kv0, int bufIdx) {
    u16_t* Kl = lds + bufIdx * 8192;
    u16_t* Vl = lds + 16384 + bufIdx * 8192;
#pragma unroll
    for (int ss = 0; ss < 4; ++ss) {
      int slot = tid + ss * 256;
      int rK = slot >> 4;
      int cK = (slot & 15) ^ ((rK & 3) | (((rK >> 3) & 1) << 2));
      __builtin_amdgcn_global_load_lds(
          (const __attribute__((address_space(1))) u32_t*)(Khead + (size_t)(kv0 + rK) * HDIM + cK * 8),
          (__attribute__((address_space(3))) u32_t*)(Kl + slot * 8), 16, 0, 0);
      int rV = slot >> 3, cV = (slot & 7) ^ (rV & 7);
      __builtin_amdgcn_global_load_lds(
          (const __attribute__((address_space(1))) u32_t*)(Vhead + (size_t)rV * SEQ + kv0 + cV * 8),
          (__attribute__((address_space(3))) u32_t*)(Vl + slot * 8), 16, 0, 0);
    }
  };

  auto qk = [&](int bufIdx, f32x4 (&Sa)[4], f32x4 (&Sb)[4]) {
    const u16_t* Kcur = lds + bufIdx * 8192;
#pragma unroll
    for (int kc = 0; kc < 4; ++kc) {
#pragma unroll
      for (int kvb = 0; kvb < 4; ++kvb) {
        int row = (l15 >> 2) * 8 + ((kvb & 1) << 2) + (l15 & 3) + ((kvb >> 1) << 5);
        int chunk = ((kc << 2) + l4) ^ (l15 & 7);
        bf16x8 kf = *(const bf16x8*)(Kcur + row * 128 + chunk * 8);
        Sa[kvb] = __builtin_amdgcn_mfma_f32_16x16x32_bf16(kf, qfa[kc], Sa[kvb], 0, 0, 0);
        Sb[kvb] = __builtin_amdgcn_mfma_f32_16x16x32_bf16(kf, qfb[kc], Sb[kvb], 0, 0, 0);
      }
    }
  };

  auto expand = [&](f32x4 (&Sa)[4], f32x4 (&Sb)[4], bf16x8 (&pfa)[2], bf16x8 (&pfb)[2]) {
    bf16x4 pa[4], pb[4];
#pragma unroll
    for (int kvb = 0; kvb < 4; ++kvb) {
#pragma unroll
      for (int r = 0; r < 4; ++r) {
        float ea = __builtin_amdgcn_exp2f(Sa[kvb][r]);
        float eb = __builtin_amdgcn_exp2f(Sb[kvb][r]);
        la += ea; lb += eb;
        pa[kvb][r] = (__bf16)ea;
        pb[kvb][r] = (__bf16)eb;
      }
    }
#pragma unroll
    for (int kc2 = 0; kc2 < 2; ++kc2) {
      uint2 alo = __builtin_bit_cast(uint2, pa[kc2 * 2]);
      uint2 ahi = __builtin_bit_cast(uint2, pa[kc2 * 2 + 1]);
      uint4 wa; wa.x = alo.x; wa.y = alo.y; wa.z = ahi.x; wa.w = ahi.y;
      pfa[kc2] = __builtin_bit_cast(bf16x8, wa);
      uint2 blo = __builtin_bit_cast(uint2, pb[kc2 * 2]);
      uint2 bhi = __builtin_bit_cast(uint2, pb[kc2 * 2 + 1]);
      uint4 wb; wb.x = blo.x; wb.y = blo.y; wb.z = bhi.x; wb.w = bhi.y;
      pfb[kc2] = __builtin_bit_cast(bf16x8, wb);
    }
  };

  auto pv = [&](int bufIdx, bf16x8 (&pfa)[2], bf16x8 (&pfb)[2]) {
    const u16_t* Vcur = lds + 16384 + bufIdx * 8192;
#pragma unroll
    for (int kc2 = 0; kc2 < 2; ++kc2) {
#pragma unroll
      for (int dcb = 0; dcb < 8; ++dcb) {
        int chunk = ((kc2 << 2) + l4) ^ (l15 & 7);
        bf16x8 vf = *(const bf16x8*)(Vcur + (dcb * 16 + l15) * 64 + chunk * 8);
        oa[dcb] = __builtin_amdgcn_mfma_f32_16x16x32_bf16(vf, pfa[kc2], oa[dcb], 0, 0, 0);
        ob[dcb] = __builtin_amdgcn_mfma_f32_16x16x32_bf16(vf, pfb[kc2], ob[dcb], 0, 0, 0);
      }
    }
  };

  auto step = [&](int t, f32x4 (&Ia)[4], f32x4 (&Ib)[4], f32x4 (&Oa)[4], f32x4 (&Ob)[4]) {
    bf16x8 pfa[2], pfb[2];
    expand(Ia, Ib, pfa, pfb);
    asm volatile("s_waitcnt vmcnt(0)" ::: "memory");
    __builtin_amdgcn_s_barrier();
    __builtin_amdgcn_sched_barrier(0);
#pragma unroll
    for (int z = 0; z < 4; ++z)
#pragma unroll
      for (int r = 0; r < 4; ++r) { Oa[z][r] = 0.f; Ob[z][r] = 0.f; }
    __builtin_amdgcn_s_setprio(1);
    pv(t & 1, pfa, pfb);
    qk((t + 1) & 1, Oa, Ob);
    __builtin_amdgcn_s_setprio(0);
    __builtin_amdgcn_sched_barrier(0);
    __builtin_amdgcn_s_barrier();
    __builtin_amdgcn_sched_barrier(0);
    if (t + 2 < SEQ / 64) stage((t + 2) * 64, t & 1);
  };

  f32x4 sA[4] = {}, sB[4] = {}, tA[4], tB[4];

  stage(0, 0);
  stage(64, 1);
  asm volatile("s_waitcnt vmcnt(8)" ::: "memory");
  __builtin_amdgcn_s_barrier();
  __builtin_amdgcn_sched_barrier(0);
  qk(0, sA, sB);

  for (int p = 0; p < 15; ++p) {
    step(2 * p, sA, sB, tA, tB);
    step(2 * p + 1, tA, tB, sA, sB);
  }
  step(30, sA, sB, tA, tB);
  {
    bf16x8 pfa[2], pfb[2];
    expand(tA, tB, pfa, pfb);
    pv(1, pfa, pfb);
  }

  la += __shfl_xor(la, 16); la += __shfl_xor(la, 32);
  lb += __shfl_xor(lb, 16); lb += __shfl_xor(lb, 32);
  float inva = 1.0f / la, invb = 1.0f / lb;

#pragma unroll
  for (int half = 0; half < 2; ++half) {
    u16_t* Owave = lds + half * 8704 + wid * 2176;
    const f32x4* oacc = half ? ob : oa;
    float inv = half ? invb : inva;
#pragma unroll
    for (int dcb = 0; dcb < 8; ++dcb) {
      bf16x4 ov;
#pragma unroll
      for (int r = 0; r < 4; ++r) ov[r] = (__bf16)(oacc[dcb][r] * inv);
      *(uint2*)(Owave + l15 * 136 + dcb * 16 + l4 * 4) = __builtin_bit_cast(uint2, ov);
    }
#pragma unroll
    for (int pass = 0; pass < 4; ++pass) {
      int rowq = pass * 4 + l4;
      int4 v = *(const int4*)(Owave + rowq * 136 + l15 * 8);
      int s = q0 + wid * 32 + half * 16 + rowq;
      *(int4*)(attn_out + ((size_t)(b * SEQ + s)) * DMODEL + h * HDIM + l15 * 8) = v;
    }
  }
}

// ---------------- launcher ----------------

extern "C" void kernel_launch(void* const* d_in, const int* in_sizes, int n_in,
                              void* d_out, int out_size, void* d_ws, size_t ws_size,
                              hipStream_t stream) {
  (void)in_sizes; (void)n_in; (void)out_size; (void)ws_size;
  const float* x  = (const float*)d_in[0];
  const float* rf = (const float*)d_in[1];
  const float* Wq = (const float*)d_in[2];
  const float* bq = (const float*)d_in[3];
  const float* Wk = (const float*)d_in[4];
  const float* bk = (const float*)d_in[5];
  const float* Wv = (const float*)d_in[6];
  const float* bv = (const float*)d_in[7];
  const float* Wo = (const float*)d_in[8];
  const float* bo = (const float*)d_in[9];
  float* out = (float*)d_out;

  char* ws = (char*)d_ws;
  u16_t* xb    = (u16_t*)ws;  ws += (size_t)MROWS * DMODEL * 2;
  u16_t* Wqkvt = (u16_t*)ws;  ws += (size_t)NQKV * DMODEL * 2;
  u16_t* Wot   = (u16_t*)ws;  ws += (size_t)DMODEL * DMODEL * 2;
  float* bqkv  = (float*)ws;  ws += (size_t)NQKV * 4;
  float* cosT  = (float*)ws;  ws += (size_t)SEQ * (HDIM / 2) * 4;
  float* sinT  = (float*)ws;  ws += (size_t)SEQ * (HDIM / 2) * 4;
  u16_t* Qb    = (u16_t*)ws;  ws += (size_t)NB * NHEAD * SEQ * HDIM * 2;
  u16_t* Kb    = (u16_t*)ws;  ws += (size_t)NB * NGRP * SEQ * HDIM * 2;
  u16_t* Vt    = (u16_t*)ws;  ws += (size_t)NB * NGRP * HDIM * SEQ * 2;
  u16_t* attn  = xb;  // alias: xb dead after GEMM1 (strict stream ordering)

  // merged prep: 8192 + 512 + 12 + 1024 + 256 + 256 + 1024 = 11276 blocks
  k_prep<<<11276, 256, 0, stream>>>(x, rf, bq, bk, bv, Wq, Wk, Wv, Wo,
                                    xb, cosT, sinT, bqkv, Wqkvt, Wot);

  // GEMM1: 4096 x 3072 x 2048, 512-thread blocks
  k_gemm<1><<<dim3(NQKV / 128, MROWS / 128), 512, 0, stream>>>(
      xb, Wqkvt, bqkv, nullptr, Qb, Kb, Vt, cosT, sinT, MROWS, NQKV, DMODEL);

  dim3 ga(SEQ / 128, NB * NHEAD);
  k_attn<<<ga, 256, 0, stream>>>(Qb, Kb, Vt, attn);

  // GEMM2: 4096 x 2048 x 2048, 512-thread blocks
  k_gemm<0><<<dim3(DMODEL / 128, MROWS / 128), 512, 0, stream>>>(
      attn, Wot, bo, out, nullptr, nullptr, nullptr, nullptr, nullptr, MROWS, DMODEL, DMODEL);
}